// Round 2
// baseline (1741.464 us; speedup 1.0000x reference)
//
#include <hip/hip_runtime.h>
#include <hip/hip_bf16.h>
#include <stdint.h>

// ---------------- problem constants ----------------
#define B_    2
#define S_    2048
#define DIM_  2048
#define H_    16
#define QL_   1536
#define KVL_  512
#define DN_   128
#define DR_   64
#define DV_   128
#define DQK_  192
#define NKV_  576     // KVL_ + DR_
#define NKVP_ 640     // padded to multiple of 128
#define BS_   (B_*S_)
#define SCALE_ 0.07216878364870322f   // 192^-0.5

typedef __hip_bfloat16 bf16;
typedef float f32x4 __attribute__((ext_vector_type(4)));
typedef short bf16x8 __attribute__((ext_vector_type(8)));   // 8 bf16 (4 VGPRs)

// ---------------- GEMM (C = A @ B^T), m97-style ----------------
#define BMT 128
#define BNT 128
#define BKT 64

__device__ __forceinline__ void gload_lds16(const void* g, void* l) {
#if __has_builtin(__builtin_amdgcn_global_load_lds)
  __builtin_amdgcn_global_load_lds(
      (const __attribute__((address_space(1))) void*)g,
      (__attribute__((address_space(3))) void*)l, 16, 0, 0);
#else
  *(uint4*)l = *(const uint4*)g;   // fallback: same addressing (base + lane*16)
#endif
}

// A: M x K (row-major, lda), B: N x K (row-major, ldb)  -> C: M x N (ldc)
// per-z offsets: saz/sbz/scz elements.  flags: 1 = fp32 C (else bf16),
// 2 = causal block skip (scores), 4 = causal K-limit (PV).
__global__ __launch_bounds__(256) void gemm_bt(
    const bf16* __restrict__ A, long lda, long saz,
    const bf16* __restrict__ Bm, long ldb, long sbz,
    void* __restrict__ Cv, long ldc, long scz,
    int K, int flags)
{
  int z = blockIdx.z;
  A  += (long)z * saz;
  Bm += (long)z * sbz;
  long coff = (long)z * scz;

  int row0 = blockIdx.y * BMT, col0 = blockIdx.x * BNT;
  if ((flags & 2) && col0 > row0 + (BMT - 1)) return;   // fully masked block
  int kend = K;
  if (flags & 4) { int lim = row0 + BMT; if (lim < kend) kend = lim; }

  // LDS: row-major [128 rows][8 x 16B chunks]; logical k-chunk j stored at
  // physical jx = j ^ (row&7)  -> staging stays lane-contiguous (wave-uniform
  // base + lane*16) AND ds_read_b128 hits <=2-way bank conflicts (free, m136).
  __shared__ __align__(16) bf16 Asm[BMT * BKT];
  __shared__ __align__(16) bf16 Bsm[BNT * BKT];

  int tid = threadIdx.x, lane = tid & 63, wave = tid >> 6;
  int wm = (wave >> 1) * 64, wn = (wave & 1) * 64;
  int quad = lane >> 4, l16 = lane & 15;

  f32x4 acc[4][4] = {};

  for (int k0 = 0; k0 < kend; k0 += BKT) {
    __syncthreads();
#pragma unroll
    for (int t = 0; t < 4; ++t) {
      int c = (wave * 4 + t) * 64 + lane;        // 16B chunk id 0..1023
      int m = c >> 3, jx = c & 7, j = jx ^ (m & 7);
      gload_lds16(A  + (long)(row0 + m) * lda + (k0 + j * 8), Asm + c * 8);
      gload_lds16(Bm + (long)(col0 + m) * ldb + (k0 + j * 8), Bsm + c * 8);
    }
    __syncthreads();   // compiler drains vmcnt(0) before s_barrier
#pragma unroll
    for (int kk = 0; kk < BKT; kk += 32) {
      int jl = (kk >> 3) + quad;                 // logical k-chunk for this quad
      bf16x8 af[4], bfv[4];
#pragma unroll
      for (int i = 0; i < 4; ++i) {
        int m = wm + i * 16 + l16;
        af[i]  = *(const bf16x8*)(Asm + m * 64 + ((jl ^ (m & 7)) * 8));
        int n = wn + i * 16 + l16;
        bfv[i] = *(const bf16x8*)(Bsm + n * 64 + ((jl ^ (n & 7)) * 8));
      }
#pragma unroll
      for (int i = 0; i < 4; ++i)
#pragma unroll
        for (int jn = 0; jn < 4; ++jn)
          acc[i][jn] = __builtin_amdgcn_mfma_f32_16x16x32_bf16(af[i], bfv[jn], acc[i][jn], 0, 0, 0);
    }
  }

  // epilogue: C/D layout col=lane&15, row=quad*4+reg (m89/m91 verified)
  if (flags & 1) {
    float* C = (float*)Cv + coff;
#pragma unroll
    for (int i = 0; i < 4; ++i)
#pragma unroll
      for (int jn = 0; jn < 4; ++jn)
#pragma unroll
        for (int r = 0; r < 4; ++r) {
          long rr = row0 + wm + i * 16 + quad * 4 + r;
          long cc = col0 + wn + jn * 16 + l16;
          C[rr * ldc + cc] = acc[i][jn][r];
        }
  } else {
    bf16* C = (bf16*)Cv + coff;
#pragma unroll
    for (int i = 0; i < 4; ++i)
#pragma unroll
      for (int jn = 0; jn < 4; ++jn)
#pragma unroll
        for (int r = 0; r < 4; ++r) {
          long rr = row0 + wm + i * 16 + quad * 4 + r;
          long cc = col0 + wn + jn * 16 + l16;
          C[rr * ldc + cc] = __float2bfloat16(acc[i][jn][r]);
        }
  }
}

// ---------------- helpers ----------------
__device__ __forceinline__ float wsum(float v) {
#pragma unroll
  for (int o = 32; o > 0; o >>= 1) v += __shfl_down(v, o, 64);
  return v;
}

__global__ __launch_bounds__(256) void cvt(const float* __restrict__ in, bf16* __restrict__ o, long n) {
  long i = (long)blockIdx.x * 256 + threadIdx.x;
  long st = (long)gridDim.x * 256;
  for (; i < n; i += st) o[i] = __float2bfloat16(in[i]);
}

__global__ __launch_bounds__(256) void cvt_pad(const float* __restrict__ in, bf16* __restrict__ o,
                                               long nvalid, long ntotal) {
  long i = (long)blockIdx.x * 256 + threadIdx.x;
  long st = (long)gridDim.x * 256;
  for (; i < ntotal; i += st) o[i] = (i < nvalid) ? __float2bfloat16(in[i]) : __float2bfloat16(0.f);
}

// w_nopeT[h][c][d] = wkv_b[(h*256+d)*512 + c]   (h<16, c<512, d<128)
__global__ __launch_bounds__(256) void build_wnopeT(const float* __restrict__ wkv_b, bf16* __restrict__ o) {
  long i = (long)blockIdx.x * 256 + threadIdx.x;   // over 16*512*128 = 1,048,576
  int d = (int)(i & 127);
  long t = i >> 7;
  int c = (int)(t & 511);
  int h = (int)(t >> 9);
  o[i] = __float2bfloat16(wkv_b[((long)(h * 256 + d)) * 512 + c]);
}

// in-place RMSNorm of qa rows (1536), bf16
__global__ __launch_bounds__(256) void rmsnorm_qa(bf16* __restrict__ qa, const float* __restrict__ w) {
  long row = blockIdx.x;
  bf16* pr = qa + row * QL_;
  int tid = threadIdx.x, lane = tid & 63, wave = tid >> 6;
  float v[6]; float ss = 0.f;
#pragma unroll
  for (int k = 0; k < 6; ++k) { int c = tid + k * 256; v[k] = __bfloat162float(pr[c]); ss += v[k] * v[k]; }
  ss = wsum(ss);
  __shared__ float sred[4];
  if (lane == 0) sred[wave] = ss;
  __syncthreads();
  float tot = sred[0] + sred[1] + sred[2] + sred[3];
  float scl = rsqrtf(tot / (float)QL_ + 1e-6f);
#pragma unroll
  for (int k = 0; k < 6; ++k) { int c = tid + k * 256; pr[c] = __float2bfloat16(v[k] * scl * w[c]); }
}

// kv row postproc: RMSNorm(kv_c)*w -> k_full[0:512], rope(k_pe) -> k_full[512:576]
__global__ __launch_bounds__(256) void kv_post(const float* __restrict__ kvraw, const float* __restrict__ kvw,
                                               const float* __restrict__ cosb, const float* __restrict__ sinb,
                                               bf16* __restrict__ kfull) {
  int bs = blockIdx.x;
  int s = bs & (S_ - 1);
  const float* rowp = kvraw + (long)bs * NKVP_;
  bf16* outp = kfull + (long)bs * NKV_;
  int tid = threadIdx.x, lane = tid & 63, wave = tid >> 6;
  float v0 = rowp[tid], v1 = rowp[tid + 256];
  float ss = v0 * v0 + v1 * v1;
  ss = wsum(ss);
  __shared__ float sred[4];
  if (lane == 0) sred[wave] = ss;
  __syncthreads();
  float tot = sred[0] + sred[1] + sred[2] + sred[3];
  float scl = rsqrtf(tot / (float)KVL_ + 1e-6f);
  outp[tid]       = __float2bfloat16(v0 * scl * kvw[tid]);
  outp[tid + 256] = __float2bfloat16(v1 * scl * kvw[tid + 256]);
  if (tid < 32) {
    float x0 = rowp[KVL_ + 2 * tid], x1 = rowp[KVL_ + 2 * tid + 1];
    float c = cosb[s * 32 + tid], sn = sinb[s * 32 + tid];
    outp[KVL_ + 2 * tid]     = __float2bfloat16(x0 * c - x1 * sn);
    outp[KVL_ + 2 * tid + 1] = __float2bfloat16(x0 * sn + x1 * c);
  }
}

// rope(q_pe) for one (b, head-pair) chunk -> qfull_c[s][hh][512:576]
// qsrc = qb + b*S_*3072 + hq*2*192
__global__ __launch_bounds__(256) void q_post_chunk(const bf16* __restrict__ qsrc,
                                                    const float* __restrict__ cosb, const float* __restrict__ sinb,
                                                    bf16* __restrict__ qfc) {
  int tx = threadIdx.x & 31, ty = threadIdx.x >> 5;
  int idx = blockIdx.x * 8 + ty;        // 0..4095 = s*2 + hh
  int s = idx >> 1, hh = idx & 1;
  const bf16* src = qsrc + (long)s * (H_ * DQK_) + hh * DQK_ + DN_;
  bf16* dst = qfc + ((long)s * 2 + hh) * NKV_ + KVL_;
  float x0 = __bfloat162float(src[2 * tx]), x1 = __bfloat162float(src[2 * tx + 1]);
  float c = cosb[s * 32 + tx], sn = sinb[s * 32 + tx];
  dst[2 * tx]     = __float2bfloat16(x0 * c - x1 * sn);
  dst[2 * tx + 1] = __float2bfloat16(x0 * sn + x1 * c);
}

// kv_cT[b][c][s] = k_full[b][s][c]  (c < 512)
__global__ __launch_bounds__(256) void transpose_kv(const bf16* __restrict__ kfull, bf16* __restrict__ kvT) {
  __shared__ bf16 tile[32][33];
  int b = blockIdx.z;
  int s0 = blockIdx.x * 32, c0 = blockIdx.y * 32;
  int tx = threadIdx.x & 31, ty = threadIdx.x >> 5;   // 8 rows per pass
#pragma unroll
  for (int r = 0; r < 4; ++r) {
    int s = s0 + ty + r * 8;
    tile[ty + r * 8][tx] = kfull[((long)b * S_ + s) * NKV_ + c0 + tx];
  }
  __syncthreads();
#pragma unroll
  for (int r = 0; r < 4; ++r) {
    int c = c0 + ty + r * 8;
    kvT[(long)b * KVL_ * S_ + (long)c * S_ + s0 + tx] = tile[tx][ty + r * 8];
  }
}

// causal softmax over one row; reads fp32 scores, writes bf16 P in place
__global__ __launch_bounds__(256) void softmax_causal(float* __restrict__ sc) {
  int r = blockIdx.x, pair = blockIdx.y;
  int tid = threadIdx.x, lane = tid & 63, wave = tid >> 6;
  const float* row = sc + ((long)pair * S_ + r) * S_;
  bf16* orow = (bf16*)sc + (long)pair * 2 * S_ * S_ + (long)r * 2 * S_;
  float v[8];
  float mx = -3.0e38f;
#pragma unroll
  for (int k = 0; k < 8; ++k) {
    int t = tid + k * 256;
    v[k] = (t <= r) ? row[t] * SCALE_ : -3.0e38f;
    mx = fmaxf(mx, v[k]);
  }
  __shared__ float smx[4];
#pragma unroll
  for (int o = 32; o > 0; o >>= 1) mx = fmaxf(mx, __shfl_down(mx, o, 64));
  if (lane == 0) smx[wave] = mx;
  __syncthreads();   // all reads of `row` complete before in-place writes
  mx = fmaxf(fmaxf(smx[0], smx[1]), fmaxf(smx[2], smx[3]));
  float s = 0.f;
#pragma unroll
  for (int k = 0; k < 8; ++k) {
    int t = tid + k * 256;
    v[k] = (t <= r) ? __expf(v[k] - mx) : 0.f;
    s += v[k];
  }
  s = wsum(s);
  __shared__ float ssm[4];
  if (lane == 0) ssm[wave] = s;
  __syncthreads();
  float inv = 1.f / (ssm[0] + ssm[1] + ssm[2] + ssm[3]);
#pragma unroll
  for (int k = 0; k < 8; ++k) {
    int t = tid + k * 256;
    orow[t] = __float2bfloat16(v[k] * inv);
  }
}

// ---------------- host ----------------
static inline void gemm(hipStream_t st, const bf16* A, long lda, long saz,
                        const bf16* Bp, long ldb, long sbz,
                        void* C, long ldc, long scz,
                        int M, int N, int K, int Z, int flags) {
  dim3 g(N / BNT, M / BMT, Z), blk(256);
  gemm_bt<<<g, blk, 0, st>>>(A, lda, saz, Bp, ldb, sbz, C, ldc, scz, K, flags);
}

extern "C" void kernel_launch(void* const* d_in, const int* in_sizes, int n_in,
                              void* d_out, int out_size, void* d_ws, size_t ws_size,
                              hipStream_t stream) {
  const float* x     = (const float*)d_in[0];
  const float* wq_a  = (const float*)d_in[1];
  const float* qnw   = (const float*)d_in[2];
  const float* wq_b  = (const float*)d_in[3];
  const float* wkv_a = (const float*)d_in[4];
  const float* kvnw  = (const float*)d_in[5];
  const float* wkv_b = (const float*)d_in[6];
  const float* wo    = (const float*)d_in[7];
  const float* cosb  = (const float*)d_in[8];
  const float* sinb  = (const float*)d_in[9];
  float* out = (float*)d_out;
  (void)in_sizes; (void)n_in; (void)out_size; (void)ws_size;

  // ---- workspace layout (total ~106 MiB), explicit overlays ----
  char* base = (char*)d_ws;
  long off = 0;
  auto at = [&](long bytes) { char* r = base + off; off += bytes; return r; };

  // E region (early phase; all dead before the attention loop) -- 45,088,768 B
  bf16*  xb    = (bf16*) at(16777216L);   // 4096x2048 bf16
  bf16*  wqab  = (bf16*) at(6291456L);    // 1536x2048 bf16
  bf16*  wqbb  = (bf16*) at(9437184L);    // 3072x1536 bf16
  bf16*  qa    = (bf16*) at(12582912L);   // 4096x1536 bf16
  float* kvraw = (float*)qa;              // overlay on qa: 4096x640 fp32 (10.5MB), written after qa dead

  // loop overlay on E base (42,467,328 B <= 45,088,768 B), used after E dead
  float* scores_c = (float*)base;                          // 2x2048x2048 fp32
  bf16*  qfull_c  = (bf16*)(base + 33554432L);             // 2048x2x576  bf16
  bf16*  ob_c     = (bf16*)(base + 33554432L + 4718592L);  // 2048x2x512  bf16

  // P region (persistent) -- 65,536,000 B ; total = 110,624,768 B
  bf16* qb    = (bf16*)at(25165824L);   // 4096x3072 bf16
  bf16* ovb   = (bf16*)at(16777216L);   // 4096x2048 bf16
  bf16* kfull = (bf16*)at(4718592L);    // 4096x576  bf16
  bf16* kvT   = (bf16*)at(4194304L);    // 2x512x2048 bf16
  bf16* wkvbb = (bf16*)at(4194304L);    // 4096x512  bf16
  bf16* wnT   = (bf16*)at(2097152L);    // 16x512x128 bf16 (w_nope transposed per head)
  bf16* wob   = (bf16*)at(8388608L);    // 2048x2048 bf16

  // bf16 conversions (d_ws re-poisoned every call, so always redo)
  cvt<<<4096, 256, 0, stream>>>(x, xb, (long)BS_ * DIM_);
  cvt<<<4096, 256, 0, stream>>>(wq_a, wqab, (long)QL_ * DIM_);
  cvt<<<4096, 256, 0, stream>>>(wq_b, wqbb, (long)H_ * DQK_ * QL_);
  cvt<<<4096, 256, 0, stream>>>(wkv_b, wkvbb, (long)H_ * 256 * KVL_);
  build_wnopeT<<<4096, 256, 0, stream>>>(wkv_b, wnT);
  cvt<<<4096, 256, 0, stream>>>(wo, wob, (long)DIM_ * H_ * DV_);

  // q path: qa = x@wq_a^T -> rmsnorm -> qb = qa@wq_b^T
  gemm(stream, xb, DIM_, 0, wqab, DIM_, 0, qa, QL_, 0, BS_, QL_, DIM_, 1, 0);
  rmsnorm_qa<<<BS_, 256, 0, stream>>>(qa, qnw);
  gemm(stream, qa, QL_, 0, wqbb, QL_, 0, qb, H_ * DQK_, 0, BS_, H_ * DQK_, QL_, 1, 0);

  // kv path.  wkv_a (bf16, padded 576->640 rows) temporarily lives in kvT,
  // which is only written by transpose_kv AFTER this gemm consumed it.
  {
    bf16* wkvab = kvT;   // 640*2048*2 = 2.62MB <= 4.19MB
    cvt_pad<<<4096, 256, 0, stream>>>(wkv_a, wkvab, (long)NKV_ * DIM_, (long)NKVP_ * DIM_);
    gemm(stream, xb, DIM_, 0, wkvab, DIM_, 0, kvraw, NKVP_, 0, BS_, NKVP_, DIM_, 1, 1);
  }
  kv_post<<<BS_, 256, 0, stream>>>(kvraw, kvnw, cosb, sinb, kfull);
  transpose_kv<<<dim3(S_ / 32, KVL_ / 32, B_), 256, 0, stream>>>(kfull, kvT);

  // attention: per (batch b, head-pair hq) chunk
  for (int ch = 0; ch < 16; ++ch) {
    int b = ch >> 3, hq = ch & 7;
    const bf16* qsrc = qb + (long)b * S_ * (H_ * DQK_) + hq * 2 * DQK_;

    // q_abs: qfull_c[s][hh][0:512] = q_nope @ w_nopeT[h]^T
    gemm(stream, qsrc, H_ * DQK_, DQK_, wnT + (long)hq * 2 * KVL_ * DN_, DN_, (long)KVL_ * DN_,
         qfull_c, 2 * NKV_, NKV_, S_, KVL_, DN_, 2, 0);
    // rope(q_pe) -> qfull_c[s][hh][512:576]
    q_post_chunk<<<512, 256, 0, stream>>>(qsrc, cosb, sinb, qfull_c);

    // scores = qfull_c @ kfull^T  (fp32, causal block skip)
    gemm(stream, qfull_c, 2 * NKV_, NKV_, kfull + (long)b * S_ * NKV_, NKV_, 0,
         scores_c, S_, (long)S_ * S_, S_, S_, NKV_, 2, 1 | 2);
    // softmax (in-place, bf16 P out)
    softmax_causal<<<dim3(S_, 2), 256, 0, stream>>>(scores_c);
    // PV: ob_c = P @ kv_cT^T  (causal K-limit)
    gemm(stream, (const bf16*)scores_c, 2 * S_, (long)S_ * 2 * S_,
         kvT + (long)b * KVL_ * S_, S_, 0,
         ob_c, 2 * KVL_, KVL_, S_, KVL_, S_, 2, 4);
    // o @ w_v^T -> ovb rows/cols of this (b, head-pair)
    gemm(stream, ob_c, 2 * KVL_, KVL_,
         wkvbb + ((long)hq * 2 * 256 + DN_) * KVL_, KVL_, (long)256 * KVL_,
         ovb + (long)b * S_ * (H_ * DV_) + hq * 2 * DV_, H_ * DV_, DV_,
         S_, DV_, KVL_, 2, 0);
  }

  // final projection: out = ovb @ wo^T (fp32 out)
  gemm(stream, ovb, H_ * DV_, 0, wob, H_ * DV_, 0, out, DIM_, 0, BS_, DIM_, H_ * DV_, 1, 1);
}

// Round 3
// 966.905 us; speedup vs baseline: 1.8011x; 1.8011x over previous
//
#include <hip/hip_runtime.h>
#include <hip/hip_bf16.h>
#include <stdint.h>

// ---------------- problem constants ----------------
#define B_    2
#define S_    2048
#define DIM_  2048
#define H_    16
#define QL_   1536
#define KVL_  512
#define DN_   128
#define DR_   64
#define DV_   128
#define DQK_  192
#define NKV_  576     // KVL_ + DR_
#define NKVP_ 640     // padded to multiple of 128
#define BS_   (B_*S_)
#define SCALE_ 0.07216878364870322f   // 192^-0.5

typedef __hip_bfloat16 bf16;
typedef float f32x4 __attribute__((ext_vector_type(4)));
typedef short bf16x8 __attribute__((ext_vector_type(8)));   // 8 bf16 (4 VGPRs)

// ---------------- GEMM (C = A @ B^T), m97-style ----------------
#define BMT 128
#define BNT 128
#define BKT 64

__device__ __forceinline__ void gload_lds16(const void* g, void* l) {
#if __has_builtin(__builtin_amdgcn_global_load_lds)
  __builtin_amdgcn_global_load_lds(
      (const __attribute__((address_space(1))) void*)g,
      (__attribute__((address_space(3))) void*)l, 16, 0, 0);
#else
  *(uint4*)l = *(const uint4*)g;   // fallback: same addressing (base + lane*16)
#endif
}

// A: M x K (row-major, lda), B: N x K (row-major, ldb)  -> C: M x N (ldc)
// per-z offsets: saz/sbz/scz elements.  flags: 1 = fp32 C (else bf16),
// 2 = causal block skip (scores), 4 = causal K-limit (PV).
__global__ __launch_bounds__(256) void gemm_bt(
    const bf16* __restrict__ A, long lda, long saz,
    const bf16* __restrict__ Bm, long ldb, long sbz,
    void* __restrict__ Cv, long ldc, long scz,
    int K, int flags)
{
  int z = blockIdx.z;
  A  += (long)z * saz;
  Bm += (long)z * sbz;
  long coff = (long)z * scz;

  int row0 = blockIdx.y * BMT, col0 = blockIdx.x * BNT;
  if ((flags & 2) && col0 > row0 + (BMT - 1)) return;   // fully masked block
  int kend = K;
  if (flags & 4) { int lim = row0 + BMT; if (lim < kend) kend = lim; }

  // LDS: row-major [128 rows][8 x 16B chunks]; logical k-chunk j stored at
  // physical jx = j ^ (row&7)  -> staging stays lane-contiguous (wave-uniform
  // base + lane*16) AND ds_read_b128 hits <=2-way bank conflicts (free, m136).
  __shared__ __align__(16) bf16 Asm[BMT * BKT];
  __shared__ __align__(16) bf16 Bsm[BNT * BKT];

  int tid = threadIdx.x, lane = tid & 63, wave = tid >> 6;
  int wm = (wave >> 1) * 64, wn = (wave & 1) * 64;
  int quad = lane >> 4, l16 = lane & 15;

  f32x4 acc[4][4] = {};

  for (int k0 = 0; k0 < kend; k0 += BKT) {
    __syncthreads();
#pragma unroll
    for (int t = 0; t < 4; ++t) {
      int c = (wave * 4 + t) * 64 + lane;        // 16B chunk id 0..1023
      int m = c >> 3, jx = c & 7, j = jx ^ (m & 7);
      gload_lds16(A  + (long)(row0 + m) * lda + (k0 + j * 8), Asm + c * 8);
      gload_lds16(Bm + (long)(col0 + m) * ldb + (k0 + j * 8), Bsm + c * 8);
    }
    __syncthreads();   // compiler drains vmcnt(0) before s_barrier
#pragma unroll
    for (int kk = 0; kk < BKT; kk += 32) {
      int jl = (kk >> 3) + quad;                 // logical k-chunk for this quad
      bf16x8 af[4], bfv[4];
#pragma unroll
      for (int i = 0; i < 4; ++i) {
        int m = wm + i * 16 + l16;
        af[i]  = *(const bf16x8*)(Asm + m * 64 + ((jl ^ (m & 7)) * 8));
        int n = wn + i * 16 + l16;
        bfv[i] = *(const bf16x8*)(Bsm + n * 64 + ((jl ^ (n & 7)) * 8));
      }
#pragma unroll
      for (int i = 0; i < 4; ++i)
#pragma unroll
        for (int jn = 0; jn < 4; ++jn)
          acc[i][jn] = __builtin_amdgcn_mfma_f32_16x16x32_bf16(af[i], bfv[jn], acc[i][jn], 0, 0, 0);
    }
  }

  // epilogue: C/D layout col=lane&15, row=quad*4+reg (m89/m91 verified)
  if (flags & 1) {
    float* C = (float*)Cv + coff;
#pragma unroll
    for (int i = 0; i < 4; ++i)
#pragma unroll
      for (int jn = 0; jn < 4; ++jn)
#pragma unroll
        for (int r = 0; r < 4; ++r) {
          long rr = row0 + wm + i * 16 + quad * 4 + r;
          long cc = col0 + wn + jn * 16 + l16;
          C[rr * ldc + cc] = acc[i][jn][r];
        }
  } else {
    bf16* C = (bf16*)Cv + coff;
#pragma unroll
    for (int i = 0; i < 4; ++i)
#pragma unroll
      for (int jn = 0; jn < 4; ++jn)
#pragma unroll
        for (int r = 0; r < 4; ++r) {
          long rr = row0 + wm + i * 16 + quad * 4 + r;
          long cc = col0 + wn + jn * 16 + l16;
          C[rr * ldc + cc] = __float2bfloat16(acc[i][jn][r]);
        }
  }
}

// ---------------- helpers ----------------
__device__ __forceinline__ float wsum(float v) {
#pragma unroll
  for (int o = 32; o > 0; o >>= 1) v += __shfl_down(v, o, 64);
  return v;
}

__global__ __launch_bounds__(256) void cvt(const float* __restrict__ in, bf16* __restrict__ o, long n) {
  long i = (long)blockIdx.x * 256 + threadIdx.x;
  long st = (long)gridDim.x * 256;
  for (; i < n; i += st) o[i] = __float2bfloat16(in[i]);
}

__global__ __launch_bounds__(256) void cvt_pad(const float* __restrict__ in, bf16* __restrict__ o,
                                               long nvalid, long ntotal) {
  long i = (long)blockIdx.x * 256 + threadIdx.x;
  long st = (long)gridDim.x * 256;
  for (; i < ntotal; i += st) o[i] = (i < nvalid) ? __float2bfloat16(in[i]) : __float2bfloat16(0.f);
}

// w_nopeT[h][c][d] = wkv_b[(h*256+d)*512 + c]   (h<16, c<512, d<128)
__global__ __launch_bounds__(256) void build_wnopeT(const float* __restrict__ wkv_b, bf16* __restrict__ o) {
  long i = (long)blockIdx.x * 256 + threadIdx.x;   // over 16*512*128 = 1,048,576
  int d = (int)(i & 127);
  long t = i >> 7;
  int c = (int)(t & 511);
  int h = (int)(t >> 9);
  o[i] = __float2bfloat16(wkv_b[((long)(h * 256 + d)) * 512 + c]);
}

// in-place RMSNorm of qa rows (1536), bf16
__global__ __launch_bounds__(256) void rmsnorm_qa(bf16* __restrict__ qa, const float* __restrict__ w) {
  long row = blockIdx.x;
  bf16* pr = qa + row * QL_;
  int tid = threadIdx.x, lane = tid & 63, wave = tid >> 6;
  float v[6]; float ss = 0.f;
#pragma unroll
  for (int k = 0; k < 6; ++k) { int c = tid + k * 256; v[k] = __bfloat162float(pr[c]); ss += v[k] * v[k]; }
  ss = wsum(ss);
  __shared__ float sred[4];
  if (lane == 0) sred[wave] = ss;
  __syncthreads();
  float tot = sred[0] + sred[1] + sred[2] + sred[3];
  float scl = rsqrtf(tot / (float)QL_ + 1e-6f);
#pragma unroll
  for (int k = 0; k < 6; ++k) { int c = tid + k * 256; pr[c] = __float2bfloat16(v[k] * scl * w[c]); }
}

// kv row postproc: RMSNorm(kv_c)*w -> k_full[0:512], rope(k_pe) -> k_full[512:576]
__global__ __launch_bounds__(256) void kv_post(const float* __restrict__ kvraw, const float* __restrict__ kvw,
                                               const float* __restrict__ cosb, const float* __restrict__ sinb,
                                               bf16* __restrict__ kfull) {
  int bs = blockIdx.x;
  int s = bs & (S_ - 1);
  const float* rowp = kvraw + (long)bs * NKVP_;
  bf16* outp = kfull + (long)bs * NKV_;
  int tid = threadIdx.x, lane = tid & 63, wave = tid >> 6;
  float v0 = rowp[tid], v1 = rowp[tid + 256];
  float ss = v0 * v0 + v1 * v1;
  ss = wsum(ss);
  __shared__ float sred[4];
  if (lane == 0) sred[wave] = ss;
  __syncthreads();
  float tot = sred[0] + sred[1] + sred[2] + sred[3];
  float scl = rsqrtf(tot / (float)KVL_ + 1e-6f);
  outp[tid]       = __float2bfloat16(v0 * scl * kvw[tid]);
  outp[tid + 256] = __float2bfloat16(v1 * scl * kvw[tid + 256]);
  if (tid < 32) {
    float x0 = rowp[KVL_ + 2 * tid], x1 = rowp[KVL_ + 2 * tid + 1];
    float c = cosb[s * 32 + tid], sn = sinb[s * 32 + tid];
    outp[KVL_ + 2 * tid]     = __float2bfloat16(x0 * c - x1 * sn);
    outp[KVL_ + 2 * tid + 1] = __float2bfloat16(x0 * sn + x1 * c);
  }
}

// rope(q_pe) for one (b, hc-head) chunk -> qfc[s*hc+hh][512:576]
// qsrc = qb + b*S_*3072 + h0*192 ; lg = log2(hc)
__global__ __launch_bounds__(256) void q_post_chunk(const bf16* __restrict__ qsrc,
                                                    const float* __restrict__ cosb, const float* __restrict__ sinb,
                                                    bf16* __restrict__ qfc, int lg) {
  int tx = threadIdx.x & 31, ty = threadIdx.x >> 5;
  int idx = blockIdx.x * 8 + ty;        // 0..S*hc-1 = s*hc + hh
  int s = idx >> lg, hh = idx & ((1 << lg) - 1);
  const bf16* src = qsrc + (long)s * (H_ * DQK_) + hh * DQK_ + DN_;
  bf16* dst = qfc + (long)idx * NKV_ + KVL_;
  float x0 = __bfloat162float(src[2 * tx]), x1 = __bfloat162float(src[2 * tx + 1]);
  float c = cosb[s * 32 + tx], sn = sinb[s * 32 + tx];
  dst[2 * tx]     = __float2bfloat16(x0 * c - x1 * sn);
  dst[2 * tx + 1] = __float2bfloat16(x0 * sn + x1 * c);
}

// kv_cT[b][c][s] = k_full[b][s][c]  (c < 512)
__global__ __launch_bounds__(256) void transpose_kv(const bf16* __restrict__ kfull, bf16* __restrict__ kvT) {
  __shared__ bf16 tile[32][33];
  int b = blockIdx.z;
  int s0 = blockIdx.x * 32, c0 = blockIdx.y * 32;
  int tx = threadIdx.x & 31, ty = threadIdx.x >> 5;
#pragma unroll
  for (int r = 0; r < 4; ++r) {
    int s = s0 + ty + r * 8;
    tile[ty + r * 8][tx] = kfull[((long)b * S_ + s) * NKV_ + c0 + tx];
  }
  __syncthreads();
#pragma unroll
  for (int r = 0; r < 4; ++r) {
    int c = c0 + ty + r * 8;
    kvT[(long)b * KVL_ * S_ + (long)c * S_ + s0 + tx] = tile[tx][ty + r * 8];
  }
}

// causal softmax over one row of head-z; reads fp32 scores, writes bf16 P in place
__global__ __launch_bounds__(256) void softmax_causal(float* __restrict__ sc) {
  int r = blockIdx.x, z = blockIdx.y;
  int tid = threadIdx.x, lane = tid & 63, wave = tid >> 6;
  const float* row = sc + ((long)z * S_ + r) * S_;
  bf16* orow = (bf16*)sc + (long)z * 2 * S_ * S_ + (long)r * 2 * S_;
  float v[8];
  float mx = -3.0e38f;
#pragma unroll
  for (int k = 0; k < 8; ++k) {
    int t = tid + k * 256;
    v[k] = (t <= r) ? row[t] * SCALE_ : -3.0e38f;
    mx = fmaxf(mx, v[k]);
  }
  __shared__ float smx[4];
#pragma unroll
  for (int o = 32; o > 0; o >>= 1) mx = fmaxf(mx, __shfl_down(mx, o, 64));
  if (lane == 0) smx[wave] = mx;
  __syncthreads();   // all reads of `row` complete before in-place writes
  mx = fmaxf(fmaxf(smx[0], smx[1]), fmaxf(smx[2], smx[3]));
  float s = 0.f;
#pragma unroll
  for (int k = 0; k < 8; ++k) {
    int t = tid + k * 256;
    v[k] = (t <= r) ? __expf(v[k] - mx) : 0.f;
    s += v[k];
  }
  s = wsum(s);
  __shared__ float ssm[4];
  if (lane == 0) ssm[wave] = s;
  __syncthreads();
  float inv = 1.f / (ssm[0] + ssm[1] + ssm[2] + ssm[3]);
#pragma unroll
  for (int k = 0; k < 8; ++k) {
    int t = tid + k * 256;
    orow[t] = __float2bfloat16(v[k] * inv);
  }
}

// ---------------- host ----------------
static inline void gemm(hipStream_t st, const bf16* A, long lda, long saz,
                        const bf16* Bp, long ldb, long sbz,
                        void* C, long ldc, long scz,
                        int M, int N, int K, int Z, int flags) {
  dim3 g(N / BNT, M / BMT, Z), blk(256);
  gemm_bt<<<g, blk, 0, st>>>(A, lda, saz, Bp, ldb, sbz, C, ldc, scz, K, flags);
}

extern "C" void kernel_launch(void* const* d_in, const int* in_sizes, int n_in,
                              void* d_out, int out_size, void* d_ws, size_t ws_size,
                              hipStream_t stream) {
  const float* x     = (const float*)d_in[0];
  const float* wq_a  = (const float*)d_in[1];
  const float* qnw   = (const float*)d_in[2];
  const float* wq_b  = (const float*)d_in[3];
  const float* wkv_a = (const float*)d_in[4];
  const float* kvnw  = (const float*)d_in[5];
  const float* wkv_b = (const float*)d_in[6];
  const float* wo    = (const float*)d_in[7];
  const float* cosb  = (const float*)d_in[8];
  const float* sinb  = (const float*)d_in[9];
  float* out = (float*)d_out;
  (void)in_sizes; (void)n_in; (void)out_size;

  // ---- heads per attention chunk, chosen from ws_size (constant per session
  // -> identical work every call, graph-capture safe) ----
  // required = persistent(65,536,000) + max(E=45,088,768, hc*21,233,664)
  int hc, lg;
  if      (ws_size >= 405274624UL + 65536) { hc = 16; lg = 4; }
  else if (ws_size >= 235405312UL + 65536) { hc = 8;  lg = 3; }
  else if (ws_size >= 150470656UL + 65536) { hc = 4;  lg = 2; }
  else                                      { hc = 2;  lg = 1; }

  // ---- workspace: persistent region first, E/loop overlay after ----
  char* base = (char*)d_ws;
  long off = 0;
  auto at = [&](long bytes) { char* r = base + off; off += bytes; return r; };

  // P region (persistent across the whole call) -- 65,536,000 B
  bf16* qb    = (bf16*)at(25165824L);   // 4096x3072 bf16
  bf16* ovb   = (bf16*)at(16777216L);   // 4096x2048 bf16
  bf16* kfull = (bf16*)at(4718592L);    // 4096x576  bf16
  bf16* kvT   = (bf16*)at(4194304L);    // 2x512x2048 bf16
  bf16* wkvbb = (bf16*)at(4194304L);    // 4096x512  bf16
  bf16* wnT   = (bf16*)at(2097152L);    // 16x512x128 bf16
  bf16* wob   = (bf16*)at(8388608L);    // 2048x2048 bf16
  char* ov = base + off;                // overlay region

  // E overlay (early phase; all dead before the attention loop)
  bf16*  xb    = (bf16*) (ov);                 // 4096x2048 bf16  (16.8MB)
  bf16*  wqab  = (bf16*) (ov + 16777216L);     // 1536x2048 bf16  (6.3MB)
  bf16*  wqbb  = (bf16*) (ov + 23068672L);     // 3072x1536 bf16  (9.4MB)
  bf16*  qa    = (bf16*) (ov + 32505856L);     // 4096x1536 bf16  (12.6MB)
  float* kvraw = (float*)qa;                   // overlay on qa (10.5MB), qa dead first

  // loop overlay (attention phase)
  float* scores_c = (float*)ov;                                  // hc x 2048x2048 fp32
  bf16*  qfull_c  = (bf16*)(ov + (long)hc * 16777216L);          // 2048 x hc x 576 bf16
  bf16*  ob_c     = (bf16*)(ov + (long)hc * (16777216L + 2359296L)); // 2048 x hc x 512 bf16

  // bf16 conversions (d_ws re-poisoned every call, so always redo)
  cvt<<<4096, 256, 0, stream>>>(x, xb, (long)BS_ * DIM_);
  cvt<<<4096, 256, 0, stream>>>(wq_a, wqab, (long)QL_ * DIM_);
  cvt<<<4096, 256, 0, stream>>>(wq_b, wqbb, (long)H_ * DQK_ * QL_);
  cvt<<<4096, 256, 0, stream>>>(wkv_b, wkvbb, (long)H_ * 256 * KVL_);
  build_wnopeT<<<4096, 256, 0, stream>>>(wkv_b, wnT);
  cvt<<<4096, 256, 0, stream>>>(wo, wob, (long)DIM_ * H_ * DV_);

  // q path: qa = x@wq_a^T -> rmsnorm -> qb = qa@wq_b^T
  gemm(stream, xb, DIM_, 0, wqab, DIM_, 0, qa, QL_, 0, BS_, QL_, DIM_, 1, 0);
  rmsnorm_qa<<<BS_, 256, 0, stream>>>(qa, qnw);
  gemm(stream, qa, QL_, 0, wqbb, QL_, 0, qb, H_ * DQK_, 0, BS_, H_ * DQK_, QL_, 1, 0);

  // kv path.  wkv_a (bf16, padded 576->640 rows) temporarily lives in kvT,
  // which is only written by transpose_kv AFTER this gemm consumed it.
  {
    bf16* wkvab = kvT;   // 640*2048*2 = 2.62MB <= 4.19MB
    cvt_pad<<<4096, 256, 0, stream>>>(wkv_a, wkvab, (long)NKV_ * DIM_, (long)NKVP_ * DIM_);
    gemm(stream, xb, DIM_, 0, wkvab, DIM_, 0, kvraw, NKVP_, 0, BS_, NKVP_, DIM_, 1, 1);
  }
  kv_post<<<BS_, 256, 0, stream>>>(kvraw, kvnw, cosb, sinb, kfull);
  transpose_kv<<<dim3(S_ / 32, KVL_ / 32, B_), 256, 0, stream>>>(kfull, kvT);

  // attention: per (batch b, hc-head group) chunk
  int nch = B_ * (H_ / hc);
  for (int ch = 0; ch < nch; ++ch) {
    int b = ch / (H_ / hc), hq = ch % (H_ / hc), h0 = hq * hc;
    const bf16* qsrc = qb + (long)b * S_ * (H_ * DQK_) + (long)h0 * DQK_;

    // q_abs: qfull_c[s*hc+z][0:512] = q_nope(head h0+z) @ w_nopeT[h0+z]^T
    gemm(stream, qsrc, H_ * DQK_, DQK_, wnT + (long)h0 * KVL_ * DN_, DN_, (long)KVL_ * DN_,
         qfull_c, (long)hc * NKV_, NKV_, S_, KVL_, DN_, hc, 0);
    // rope(q_pe) -> qfull_c[s*hc+z][512:576]
    q_post_chunk<<<S_ * hc / 8, 256, 0, stream>>>(qsrc, cosb, sinb, qfull_c, lg);

    // scores = qfull_c @ kfull^T  (fp32, causal block skip)
    gemm(stream, qfull_c, (long)hc * NKV_, NKV_, kfull + (long)b * S_ * NKV_, NKV_, 0,
         scores_c, S_, (long)S_ * S_, S_, S_, NKV_, hc, 1 | 2);
    // softmax (in-place, bf16 P out)
    softmax_causal<<<dim3(S_, hc), 256, 0, stream>>>(scores_c);
    // PV: ob_c = P @ kv_cT^T  (causal K-limit)
    gemm(stream, (const bf16*)scores_c, 2 * S_, (long)S_ * 2 * S_,
         kvT + (long)b * KVL_ * S_, S_, 0,
         ob_c, (long)hc * KVL_, KVL_, S_, KVL_, S_, hc, 4);
    // o @ w_v^T -> ovb rows/cols of this chunk
    gemm(stream, ob_c, (long)hc * KVL_, KVL_,
         wkvbb + ((long)h0 * 256 + DN_) * KVL_, KVL_, (long)256 * KVL_,
         ovb + (long)b * S_ * (H_ * DV_) + (long)h0 * DV_, H_ * DV_, DV_,
         S_, DV_, KVL_, hc, 0);
  }

  // final projection: out = ovb @ wo^T (fp32 out)
  gemm(stream, ovb, H_ * DV_, 0, wob, H_ * DV_, 0, out, DIM_, 0, BS_, DIM_, H_ * DV_, 1, 1);
}

// Round 5
// 907.328 us; speedup vs baseline: 1.9193x; 1.0657x over previous
//
#include <hip/hip_runtime.h>
#include <hip/hip_bf16.h>
#include <stdint.h>

// ---------------- problem constants ----------------
#define B_    2
#define S_    2048
#define DIM_  2048
#define H_    16
#define QL_   1536
#define KVL_  512
#define DN_   128
#define DR_   64
#define DV_   128
#define DQK_  192
#define NKV_  576     // KVL_ + DR_
#define NKVP_ 640     // padded to multiple of 128
#define BS_   (B_*S_)
#define SCALE_ 0.07216878364870322f   // 192^-0.5

typedef __hip_bfloat16 bf16;
typedef float f32x4 __attribute__((ext_vector_type(4)));
typedef short bf16x8 __attribute__((ext_vector_type(8)));   // 8 bf16 (4 VGPRs)

// ---------------- GEMM (C = A @ B^T), m97-style, shape-specialized ----------
#define BMT 128
#define BNT 128
#define BKT 64

__device__ __forceinline__ void gload_lds16(const void* g, void* l) {
#if __has_builtin(__builtin_amdgcn_global_load_lds)
  __builtin_amdgcn_global_load_lds(
      (const __attribute__((address_space(1))) void*)g,
      (__attribute__((address_space(3))) void*)l, 16, 0, 0);
#else
  *(uint4*)l = *(const uint4*)g;
#endif
}

// A: M x K (row-major, LDA), B: N x K (row-major, LDB) -> C: M x N (LDC)
// All strides/K compile-time. FLAGS: 1 = fp32 C (else bf16),
// 2 = causal block skip (scores), 4 = causal K-limit (PV).
template <int K, int LDA, int LDB, int LDC, int FLAGS>
__global__ __launch_bounds__(256) void gemm_t(
    const bf16* __restrict__ A, long saz,
    const bf16* __restrict__ Bm, long sbz,
    void* __restrict__ Cv, long scz)
{
  int z = blockIdx.z;
  A  += (long)z * saz;
  Bm += (long)z * sbz;
  long coff = (long)z * scz;

  int row0 = blockIdx.y * BMT, col0 = blockIdx.x * BNT;
  if (FLAGS & 2) { if (col0 > row0 + (BMT - 1)) return; }   // fully masked block
  int kend = K;
  if (FLAGS & 4) { int lim = row0 + BMT; if (lim < kend) kend = lim; }

  // LDS: [128 rows][8 x 16B chunks], chunk j stored at jx = j ^ (row&7):
  // staging stays lane-contiguous (wave-uniform base + lane*16) and
  // ds_read_b128 sees <=2-way bank conflicts (free, m136).
  __shared__ __align__(16) bf16 Asm[BMT * BKT];
  __shared__ __align__(16) bf16 Bsm[BNT * BKT];

  int tid = threadIdx.x, lane = tid & 63, wave = tid >> 6;
  int wm = (wave >> 1) * 64, wn = (wave & 1) * 64;
  int quad = lane >> 4, l16 = lane & 15;

  f32x4 acc[4][4] = {};

  for (int k0 = 0; k0 < kend; k0 += BKT) {
    __syncthreads();
#pragma unroll
    for (int t = 0; t < 4; ++t) {
      int c = (wave * 4 + t) * 64 + lane;        // 16B chunk id 0..1023
      int m = c >> 3, jx = c & 7, j = jx ^ (m & 7);
      gload_lds16(A  + (long)((row0 + m) * LDA + k0 + j * 8), Asm + c * 8);
      gload_lds16(Bm + (long)((col0 + m) * LDB + k0 + j * 8), Bsm + c * 8);
    }
    __syncthreads();
#pragma unroll
    for (int kk = 0; kk < BKT; kk += 32) {
      int jl = (kk >> 3) + quad;
      bf16x8 af[4], bfv[4];
#pragma unroll
      for (int i = 0; i < 4; ++i) {
        int m = wm + i * 16 + l16;
        af[i]  = *(const bf16x8*)(Asm + m * 64 + ((jl ^ (m & 7)) * 8));
        int n = wn + i * 16 + l16;
        bfv[i] = *(const bf16x8*)(Bsm + n * 64 + ((jl ^ (n & 7)) * 8));
      }
#pragma unroll
      for (int i = 0; i < 4; ++i)
#pragma unroll
        for (int jn = 0; jn < 4; ++jn)
          acc[i][jn] = __builtin_amdgcn_mfma_f32_16x16x32_bf16(af[i], bfv[jn], acc[i][jn], 0, 0, 0);
    }
  }

  // epilogue: C/D layout col=lane&15, row=quad*4+reg (m89/m91 verified)
  if (FLAGS & 1) {
    float* C = (float*)Cv + coff;
#pragma unroll
    for (int i = 0; i < 4; ++i)
#pragma unroll
      for (int jn = 0; jn < 4; ++jn)
#pragma unroll
        for (int r = 0; r < 4; ++r) {
          int rr = row0 + wm + i * 16 + quad * 4 + r;
          int cc = col0 + wn + jn * 16 + l16;
          C[(long)rr * LDC + cc] = acc[i][jn][r];
        }
  } else {
    bf16* C = (bf16*)Cv + coff;
#pragma unroll
    for (int i = 0; i < 4; ++i)
#pragma unroll
      for (int jn = 0; jn < 4; ++jn)
#pragma unroll
        for (int r = 0; r < 4; ++r) {
          int rr = row0 + wm + i * 16 + quad * 4 + r;
          int cc = col0 + wn + jn * 16 + l16;
          C[(long)rr * LDC + cc] = __float2bfloat16(acc[i][jn][r]);
        }
  }
}

template <int K, int LDA, int LDB, int LDC, int FLAGS>
static inline void G(hipStream_t st, const bf16* A, long saz, const bf16* Bp, long sbz,
                     void* C, long scz, int M, int N, int Z) {
  dim3 g(N / BNT, M / BMT, Z);
  gemm_t<K, LDA, LDB, LDC, FLAGS><<<g, 256, 0, st>>>(A, saz, Bp, sbz, C, scz);
}

// ---------------- helpers ----------------
__device__ __forceinline__ float wsum(float v) {
#pragma unroll
  for (int o = 32; o > 0; o >>= 1) v += __shfl_down(v, o, 64);
  return v;
}

// one fused conversion pass: all fp32->bf16 weight/activation copies + the
// wkv_a zero-pad + the w_nope per-head transpose. Segment bounds = exact
// element counts (fixed: wkv_b is 4096x512 = 2,097,152 elements).
#define CVT_N0  8388608L    // x -> xb            (4096*2048)
#define CVT_N1 11534336L    // wq_a -> wqab       (+1536*2048)
#define CVT_N2 16252928L    // wq_b -> wqbb       (+3072*1536)
#define CVT_N3 18350080L    // wkv_b -> wkvbb     (+4096*512)
#define CVT_N4 22544384L    // wo -> wob          (+2048*2048)
#define CVT_N5 23855104L    // wkv_a pad -> wkvab (+640*2048, valid 1179648)
#define CVT_N6 24903680L    // wnT build          (+16*512*128)
__global__ __launch_bounds__(256) void cvt_all(
    const float* __restrict__ x, const float* __restrict__ wq_a,
    const float* __restrict__ wq_b, const float* __restrict__ wkv_b,
    const float* __restrict__ wo, const float* __restrict__ wkv_a,
    bf16* __restrict__ xb, bf16* __restrict__ wqab, bf16* __restrict__ wqbb,
    bf16* __restrict__ wkvbb, bf16* __restrict__ wob, bf16* __restrict__ wkvab,
    bf16* __restrict__ wnT)
{
  for (long i = (long)blockIdx.x * 256 + threadIdx.x; i < CVT_N6; i += (long)gridDim.x * 256) {
    if (i < CVT_N0) {
      xb[i] = __float2bfloat16(x[i]);
    } else if (i < CVT_N1) {
      long j = i - CVT_N0; wqab[j] = __float2bfloat16(wq_a[j]);
    } else if (i < CVT_N2) {
      long j = i - CVT_N1; wqbb[j] = __float2bfloat16(wq_b[j]);
    } else if (i < CVT_N3) {
      long j = i - CVT_N2; wkvbb[j] = __float2bfloat16(wkv_b[j]);
    } else if (i < CVT_N4) {
      long j = i - CVT_N3; wob[j] = __float2bfloat16(wo[j]);
    } else if (i < CVT_N5) {
      long j = i - CVT_N4;
      wkvab[j] = (j < (long)NKV_ * DIM_) ? __float2bfloat16(wkv_a[j]) : __float2bfloat16(0.f);
    } else {
      long j = i - CVT_N5;                       // wnT[h][c][d] = wkv_b[(h*256+d)*512+c]
      int d = (int)(j & 127);
      long t = j >> 7;
      int c = (int)(t & 511);
      int h = (int)(t >> 9);
      wnT[j] = __float2bfloat16(wkv_b[((long)(h * 256 + d)) * 512 + c]);
    }
  }
}

// in-place RMSNorm of qa rows (1536), bf16
__global__ __launch_bounds__(256) void rmsnorm_qa(bf16* __restrict__ qa, const float* __restrict__ w) {
  long row = blockIdx.x;
  bf16* pr = qa + row * QL_;
  int tid = threadIdx.x, lane = tid & 63, wave = tid >> 6;
  float v[6]; float ss = 0.f;
#pragma unroll
  for (int k = 0; k < 6; ++k) { int c = tid + k * 256; v[k] = __bfloat162float(pr[c]); ss += v[k] * v[k]; }
  ss = wsum(ss);
  __shared__ float sred[4];
  if (lane == 0) sred[wave] = ss;
  __syncthreads();
  float tot = sred[0] + sred[1] + sred[2] + sred[3];
  float scl = rsqrtf(tot / (float)QL_ + 1e-6f);
#pragma unroll
  for (int k = 0; k < 6; ++k) { int c = tid + k * 256; pr[c] = __float2bfloat16(v[k] * scl * w[c]); }
}

// kv row postproc: RMSNorm(kv_c)*w -> k_full[0:512], rope(k_pe) -> k_full[512:576]
__global__ __launch_bounds__(256) void kv_post(const float* __restrict__ kvraw, const float* __restrict__ kvw,
                                               const float* __restrict__ cosb, const float* __restrict__ sinb,
                                               bf16* __restrict__ kfull) {
  int bs = blockIdx.x;
  int s = bs & (S_ - 1);
  const float* rowp = kvraw + (long)bs * NKVP_;
  bf16* outp = kfull + (long)bs * NKV_;
  int tid = threadIdx.x, lane = tid & 63, wave = tid >> 6;
  float v0 = rowp[tid], v1 = rowp[tid + 256];
  float ss = v0 * v0 + v1 * v1;
  ss = wsum(ss);
  __shared__ float sred[4];
  if (lane == 0) sred[wave] = ss;
  __syncthreads();
  float tot = sred[0] + sred[1] + sred[2] + sred[3];
  float scl = rsqrtf(tot / (float)KVL_ + 1e-6f);
  outp[tid]       = __float2bfloat16(v0 * scl * kvw[tid]);
  outp[tid + 256] = __float2bfloat16(v1 * scl * kvw[tid + 256]);
  if (tid < 32) {
    float x0 = rowp[KVL_ + 2 * tid], x1 = rowp[KVL_ + 2 * tid + 1];
    float c = cosb[s * 32 + tid], sn = sinb[s * 32 + tid];
    outp[KVL_ + 2 * tid]     = __float2bfloat16(x0 * c - x1 * sn);
    outp[KVL_ + 2 * tid + 1] = __float2bfloat16(x0 * sn + x1 * c);
  }
}

// rope(q_pe) for one (b, hc-head) chunk -> qfc[s*hc+hh][512:576]
__global__ __launch_bounds__(256) void q_post_chunk(const bf16* __restrict__ qsrc,
                                                    const float* __restrict__ cosb, const float* __restrict__ sinb,
                                                    bf16* __restrict__ qfc, int lg) {
  int tx = threadIdx.x & 31, ty = threadIdx.x >> 5;
  int idx = blockIdx.x * 8 + ty;        // 0..S*hc-1 = s*hc + hh
  int s = idx >> lg, hh = idx & ((1 << lg) - 1);
  const bf16* src = qsrc + (long)s * (H_ * DQK_) + hh * DQK_ + DN_;
  bf16* dst = qfc + (long)idx * NKV_ + KVL_;
  float x0 = __bfloat162float(src[2 * tx]), x1 = __bfloat162float(src[2 * tx + 1]);
  float c = cosb[s * 32 + tx], sn = sinb[s * 32 + tx];
  dst[2 * tx]     = __float2bfloat16(x0 * c - x1 * sn);
  dst[2 * tx + 1] = __float2bfloat16(x0 * sn + x1 * c);
}

// kv_cT[b][c][s] = k_full[b][s][c]  (c < 512)
__global__ __launch_bounds__(256) void transpose_kv(const bf16* __restrict__ kfull, bf16* __restrict__ kvT) {
  __shared__ bf16 tile[32][33];
  int b = blockIdx.z;
  int s0 = blockIdx.x * 32, c0 = blockIdx.y * 32;
  int tx = threadIdx.x & 31, ty = threadIdx.x >> 5;
#pragma unroll
  for (int r = 0; r < 4; ++r) {
    int s = s0 + ty + r * 8;
    tile[ty + r * 8][tx] = kfull[((long)b * S_ + s) * NKV_ + c0 + tx];
  }
  __syncthreads();
#pragma unroll
  for (int r = 0; r < 4; ++r) {
    int c = c0 + ty + r * 8;
    kvT[(long)b * KVL_ * S_ + (long)c * S_ + s0 + tx] = tile[tx][ty + r * 8];
  }
}

// causal softmax over one row of head-z; fp32 scores in, bf16 P in place.
// Stores only up to the causal block edge (PV reads k < (r&~127)+128).
__global__ __launch_bounds__(256) void softmax_causal(float* __restrict__ sc) {
  int r = blockIdx.x, z = blockIdx.y;
  int tid = threadIdx.x, lane = tid & 63, wave = tid >> 6;
  const float* row = sc + ((long)z * S_ + r) * S_;
  bf16* orow = (bf16*)sc + (long)z * 2 * S_ * S_ + (long)r * 2 * S_;
  int wlen = (r & ~127) + 128;
  float v[8];
  float mx = -3.0e38f;
#pragma unroll
  for (int k = 0; k < 8; ++k) {
    int t = tid + k * 256;
    v[k] = (t <= r) ? row[t] * SCALE_ : -3.0e38f;
    mx = fmaxf(mx, v[k]);
  }
  __shared__ float smx[4];
#pragma unroll
  for (int o = 32; o > 0; o >>= 1) mx = fmaxf(mx, __shfl_down(mx, o, 64));
  if (lane == 0) smx[wave] = mx;
  __syncthreads();   // all reads of `row` complete before in-place writes
  mx = fmaxf(fmaxf(smx[0], smx[1]), fmaxf(smx[2], smx[3]));
  float s = 0.f;
#pragma unroll
  for (int k = 0; k < 8; ++k) {
    int t = tid + k * 256;
    v[k] = (t <= r) ? __expf(v[k] - mx) : 0.f;
    s += v[k];
  }
  s = wsum(s);
  __shared__ float ssm[4];
  if (lane == 0) ssm[wave] = s;
  __syncthreads();
  float inv = 1.f / (ssm[0] + ssm[1] + ssm[2] + ssm[3]);
#pragma unroll
  for (int k = 0; k < 8; ++k) {
    int t = tid + k * 256;
    if (t < wlen) orow[t] = __float2bfloat16(v[k] * inv);
  }
}

// ---------------- attention loop (HC = heads per chunk, compile-time) -------
template <int HC>
static void attn_loop(hipStream_t stream, const bf16* qb, const bf16* wnT,
                      const bf16* kfull, const bf16* kvT, const bf16* wkvbb,
                      bf16* ovb, float* scores_c, bf16* qfull_c, bf16* ob_c,
                      const float* cosb, const float* sinb) {
  constexpr int LG = (HC == 8) ? 3 : (HC == 4) ? 2 : 1;
  const int nch = B_ * (H_ / HC);
  for (int ch = 0; ch < nch; ++ch) {
    int b = ch / (H_ / HC), hq = ch % (H_ / HC), h0 = hq * HC;
    const bf16* qsrc = qb + (long)b * S_ * (H_ * DQK_) + (long)h0 * DQK_;

    // q_abs: qfull_c[s*HC+z][0:512] = q_nope(head h0+z) @ w_nopeT[h0+z]^T
    G<DN_, H_ * DQK_, DN_, HC * NKV_, 0>(stream,
        qsrc, DQK_, wnT + (long)h0 * KVL_ * DN_, (long)KVL_ * DN_,
        qfull_c, NKV_, S_, KVL_, HC);
    // rope(q_pe) -> qfull_c[s*HC+z][512:576]
    q_post_chunk<<<S_ * HC / 8, 256, 0, stream>>>(qsrc, cosb, sinb, qfull_c, LG);

    // scores = qfull_c @ kfull^T  (fp32, causal block skip)
    G<NKV_, HC * NKV_, NKV_, S_, 1 | 2>(stream,
        qfull_c, NKV_, kfull + (long)b * S_ * NKV_, 0,
        scores_c, (long)S_ * S_, S_, S_, HC);
    // softmax (in-place, bf16 P out)
    softmax_causal<<<dim3(S_, HC), 256, 0, stream>>>(scores_c);
    // PV: ob_c = P @ kv_cT^T  (causal K-limit)
    G<S_, 2 * S_, S_, HC * KVL_, 4>(stream,
        (const bf16*)scores_c, (long)S_ * 2 * S_, kvT + (long)b * KVL_ * S_, 0,
        ob_c, KVL_, S_, KVL_, HC);
    // o @ w_v^T -> ovb rows/cols of this chunk
    G<KVL_, HC * KVL_, KVL_, H_ * DV_, 0>(stream,
        ob_c, KVL_, wkvbb + ((long)h0 * 256 + DN_) * KVL_, (long)256 * KVL_,
        ovb + (long)b * S_ * (H_ * DV_) + (long)h0 * DV_, DV_, S_, DV_, HC);
  }
}

// ---------------- host ----------------
extern "C" void kernel_launch(void* const* d_in, const int* in_sizes, int n_in,
                              void* d_out, int out_size, void* d_ws, size_t ws_size,
                              hipStream_t stream) {
  const float* x     = (const float*)d_in[0];
  const float* wq_a  = (const float*)d_in[1];
  const float* qnw   = (const float*)d_in[2];
  const float* wq_b  = (const float*)d_in[3];
  const float* wkv_a = (const float*)d_in[4];
  const float* kvnw  = (const float*)d_in[5];
  const float* wkv_b = (const float*)d_in[6];
  const float* wo    = (const float*)d_in[7];
  const float* cosb  = (const float*)d_in[8];
  const float* sinb  = (const float*)d_in[9];
  float* out = (float*)d_out;
  (void)in_sizes; (void)n_in; (void)out_size;

  // heads per attention chunk, from ws_size (constant per session -> graph-safe)
  // required = persistent(65,536,000) + max(E=45,088,768, hc*21,233,664)
  int hc;
  if      (ws_size >= 235405312UL + 65536) hc = 8;
  else if (ws_size >= 150470656UL + 65536) hc = 4;
  else                                     hc = 2;

  // ---- workspace: persistent region first, E/loop overlay after ----
  char* base = (char*)d_ws;
  long off = 0;
  auto at = [&](long bytes) { char* r = base + off; off += bytes; return r; };

  // P region (persistent across the whole call) -- 65,536,000 B
  bf16* qb    = (bf16*)at(25165824L);   // 4096x3072 bf16
  bf16* ovb   = (bf16*)at(16777216L);   // 4096x2048 bf16
  bf16* kfull = (bf16*)at(4718592L);    // 4096x576  bf16
  bf16* kvT   = (bf16*)at(4194304L);    // 2x512x2048 bf16
  bf16* wkvbb = (bf16*)at(4194304L);    // 4096x512  bf16
  bf16* wnT   = (bf16*)at(2097152L);    // 16x512x128 bf16
  bf16* wob   = (bf16*)at(8388608L);    // 2048x2048 bf16
  char* ov = base + off;                // overlay region

  // E overlay (early phase; all dead before the attention loop)
  bf16*  xb    = (bf16*) (ov);                 // 4096x2048 bf16  (16.8MB)
  bf16*  wqab  = (bf16*) (ov + 16777216L);     // 1536x2048 bf16  (6.3MB)
  bf16*  wqbb  = (bf16*) (ov + 23068672L);     // 3072x1536 bf16  (9.4MB)
  bf16*  qa    = (bf16*) (ov + 32505856L);     // 4096x1536 bf16  (12.6MB)
  float* kvraw = (float*)qa;                   // overlay on qa (10.5MB), qa dead first

  // loop overlay (attention phase)
  float* scores_c = (float*)ov;                                      // hc x 2048x2048 fp32
  bf16*  qfull_c  = (bf16*)(ov + (long)hc * 16777216L);              // 2048 x hc x 576 bf16
  bf16*  ob_c     = (bf16*)(ov + (long)hc * (16777216L + 2359296L)); // 2048 x hc x 512 bf16

  // wkv_a (bf16, padded 576->640 rows) temporarily lives in kvT, which is
  // only written by transpose_kv AFTER the kv GEMM consumed it.
  bf16* wkvab = kvT;   // 640*2048*2 = 2.62MB <= 4.19MB

  // one fused conversion pass (x, wq_a, wq_b, wkv_b, wo, wkv_a+pad, wnT)
  cvt_all<<<4096, 256, 0, stream>>>(x, wq_a, wq_b, wkv_b, wo, wkv_a,
                                    xb, wqab, wqbb, wkvbb, wob, wkvab, wnT);

  // q path: qa = x@wq_a^T -> rmsnorm -> qb = qa@wq_b^T
  G<DIM_, DIM_, DIM_, QL_, 0>(stream, xb, 0, wqab, 0, qa, 0, BS_, QL_, 1);
  rmsnorm_qa<<<BS_, 256, 0, stream>>>(qa, qnw);
  G<QL_, QL_, QL_, H_ * DQK_, 0>(stream, qa, 0, wqbb, 0, qb, 0, BS_, H_ * DQK_, 1);

  // kv path: kvraw = x@wkv_a^T (padded, fp32) -> norm+rope -> kfull, kvT
  G<DIM_, DIM_, DIM_, NKVP_, 1>(stream, xb, 0, wkvab, 0, kvraw, 0, BS_, NKVP_, 1);
  kv_post<<<BS_, 256, 0, stream>>>(kvraw, kvnw, cosb, sinb, kfull);
  transpose_kv<<<dim3(S_ / 32, KVL_ / 32, B_), 256, 0, stream>>>(kfull, kvT);

  // attention chunks
  if (hc == 8)
    attn_loop<8>(stream, qb, wnT, kfull, kvT, wkvbb, ovb, scores_c, qfull_c, ob_c, cosb, sinb);
  else if (hc == 4)
    attn_loop<4>(stream, qb, wnT, kfull, kvT, wkvbb, ovb, scores_c, qfull_c, ob_c, cosb, sinb);
  else
    attn_loop<2>(stream, qb, wnT, kfull, kvT, wkvbb, ovb, scores_c, qfull_c, ob_c, cosb, sinb);

  // final projection: out = ovb @ wo^T (fp32 out)
  G<H_ * DV_, H_ * DV_, H_ * DV_, DIM_, 1>(stream, ovb, 0, wob, 0, out, 0, BS_, DIM_, 1);
}

// Round 6
// 864.542 us; speedup vs baseline: 2.0143x; 1.0495x over previous
//
#include <hip/hip_runtime.h>
#include <hip/hip_bf16.h>
#include <stdint.h>

// ---------------- problem constants ----------------
#define B_    2
#define S_    2048
#define DIM_  2048
#define H_    16
#define QL_   1536
#define KVL_  512
#define DN_   128
#define DR_   64
#define DV_   128
#define DQK_  192
#define NKV_  576     // KVL_ + DR_
#define NKVP_ 640     // padded to multiple of 128
#define BS_   (B_*S_)
#define SCALE_ 0.07216878364870322f   // 192^-0.5

typedef __hip_bfloat16 bf16;
typedef float f32x4 __attribute__((ext_vector_type(4)));
typedef short bf16x8 __attribute__((ext_vector_type(8)));   // 8 bf16 (4 VGPRs)

// ---------------- GEMM (C = A @ B^T), m97-style, shape-specialized ----------
#define BMT 128
#define BNT 128
#define BKT 64

__device__ __forceinline__ void gload_lds16(const void* g, void* l) {
#if __has_builtin(__builtin_amdgcn_global_load_lds)
  __builtin_amdgcn_global_load_lds(
      (const __attribute__((address_space(1))) void*)g,
      (__attribute__((address_space(3))) void*)l, 16, 0, 0);
#else
  *(uint4*)l = *(const uint4*)g;
#endif
}

// A: M x K (row-major, LDA), B: N x K (row-major, LDB) -> C: M x N (LDC)
// FLAGS: 1 = fp32 C, 8 = bf16 C scaled by SCALE_, else bf16 C;
//        2 = causal block skip (scores), 4 = causal K-limit (PV).
template <int K, int LDA, int LDB, int LDC, int FLAGS>
__global__ __launch_bounds__(256) void gemm_t(
    const bf16* __restrict__ A, long saz,
    const bf16* __restrict__ Bm, long sbz,
    void* __restrict__ Cv, long scz)
{
  int z = blockIdx.z;
  A  += (long)z * saz;
  Bm += (long)z * sbz;
  long coff = (long)z * scz;

  int row0 = blockIdx.y * BMT, col0 = blockIdx.x * BNT;
  if (FLAGS & 2) { if (col0 > row0 + (BMT - 1)) return; }   // fully masked block
  int kend = K;
  if (FLAGS & 4) { int lim = row0 + BMT; if (lim < kend) kend = lim; }

  // LDS: [128 rows][8 x 16B chunks], chunk j stored at jx = j ^ (row&7):
  // staging stays lane-contiguous (wave-uniform base + lane*16) and
  // ds_read_b128 sees <=2-way bank conflicts (free, m136).
  __shared__ __align__(16) bf16 Asm[BMT * BKT];
  __shared__ __align__(16) bf16 Bsm[BNT * BKT];

  int tid = threadIdx.x, lane = tid & 63, wave = tid >> 6;
  int wm = (wave >> 1) * 64, wn = (wave & 1) * 64;
  int quad = lane >> 4, l16 = lane & 15;

  f32x4 acc[4][4] = {};

  for (int k0 = 0; k0 < kend; k0 += BKT) {
    __syncthreads();
#pragma unroll
    for (int t = 0; t < 4; ++t) {
      int c = (wave * 4 + t) * 64 + lane;        // 16B chunk id 0..1023
      int m = c >> 3, jx = c & 7, j = jx ^ (m & 7);
      gload_lds16(A  + (long)((row0 + m) * LDA + k0 + j * 8), Asm + c * 8);
      gload_lds16(Bm + (long)((col0 + m) * LDB + k0 + j * 8), Bsm + c * 8);
    }
    __syncthreads();
#pragma unroll
    for (int kk = 0; kk < BKT; kk += 32) {
      int jl = (kk >> 3) + quad;
      bf16x8 af[4], bfv[4];
#pragma unroll
      for (int i = 0; i < 4; ++i) {
        int m = wm + i * 16 + l16;
        af[i]  = *(const bf16x8*)(Asm + m * 64 + ((jl ^ (m & 7)) * 8));
        int n = wn + i * 16 + l16;
        bfv[i] = *(const bf16x8*)(Bsm + n * 64 + ((jl ^ (n & 7)) * 8));
      }
#pragma unroll
      for (int i = 0; i < 4; ++i)
#pragma unroll
        for (int jn = 0; jn < 4; ++jn)
          acc[i][jn] = __builtin_amdgcn_mfma_f32_16x16x32_bf16(af[i], bfv[jn], acc[i][jn], 0, 0, 0);
    }
  }

  // epilogue: C/D layout col=lane&15, row=quad*4+reg (m89/m91 verified)
  if (FLAGS & 1) {
    float* C = (float*)Cv + coff;
#pragma unroll
    for (int i = 0; i < 4; ++i)
#pragma unroll
      for (int jn = 0; jn < 4; ++jn)
#pragma unroll
        for (int r = 0; r < 4; ++r) {
          int rr = row0 + wm + i * 16 + quad * 4 + r;
          int cc = col0 + wn + jn * 16 + l16;
          C[(long)rr * LDC + cc] = acc[i][jn][r];
        }
  } else if (FLAGS & 8) {
    bf16* C = (bf16*)Cv + coff;
#pragma unroll
    for (int i = 0; i < 4; ++i)
#pragma unroll
      for (int jn = 0; jn < 4; ++jn)
#pragma unroll
        for (int r = 0; r < 4; ++r) {
          int rr = row0 + wm + i * 16 + quad * 4 + r;
          int cc = col0 + wn + jn * 16 + l16;
          C[(long)rr * LDC + cc] = __float2bfloat16(acc[i][jn][r] * SCALE_);
        }
  } else {
    bf16* C = (bf16*)Cv + coff;
#pragma unroll
    for (int i = 0; i < 4; ++i)
#pragma unroll
      for (int jn = 0; jn < 4; ++jn)
#pragma unroll
        for (int r = 0; r < 4; ++r) {
          int rr = row0 + wm + i * 16 + quad * 4 + r;
          int cc = col0 + wn + jn * 16 + l16;
          C[(long)rr * LDC + cc] = __float2bfloat16(acc[i][jn][r]);
        }
  }
}

template <int K, int LDA, int LDB, int LDC, int FLAGS>
static inline void G(hipStream_t st, const bf16* A, long saz, const bf16* Bp, long sbz,
                     void* C, long scz, int M, int N, int Z) {
  dim3 g(N / BNT, M / BMT, Z);
  gemm_t<K, LDA, LDB, LDC, FLAGS><<<g, 256, 0, st>>>(A, saz, Bp, sbz, C, scz);
}

// ---------------- helpers ----------------
__device__ __forceinline__ float wsum(float v) {
#pragma unroll
  for (int o = 32; o > 0; o >>= 1) v += __shfl_down(v, o, 64);
  return v;
}

// fused fp32->bf16 conversion pass, vectorized: 8 elements (two float4 loads,
// one 16B bf16x8 store) per group. All segment bases/sizes are multiples of 8
// elements, so groups never straddle segments; pad boundary (1,179,648) is
// also 8-aligned.
#define CVT_N0  8388608L    // x -> xb            (4096*2048)
#define CVT_N1 11534336L    // wq_a -> wqab       (+1536*2048)
#define CVT_N2 16252928L    // wq_b -> wqbb       (+3072*1536)
#define CVT_N3 18350080L    // wkv_b -> wkvbb     (+4096*512)
#define CVT_N4 22544384L    // wo -> wob          (+2048*2048)
#define CVT_N5 23855104L    // wkv_a pad -> wkvab (+640*2048, valid 1179648)
#define CVT_N6 24903680L    // wnT build          (+16*512*128)
__device__ __forceinline__ void cvt8(const float* __restrict__ s, bf16* __restrict__ d) {
  float4 a = ((const float4*)s)[0], b = ((const float4*)s)[1];
  __align__(16) bf16 t[8];
  t[0] = __float2bfloat16(a.x); t[1] = __float2bfloat16(a.y);
  t[2] = __float2bfloat16(a.z); t[3] = __float2bfloat16(a.w);
  t[4] = __float2bfloat16(b.x); t[5] = __float2bfloat16(b.y);
  t[6] = __float2bfloat16(b.z); t[7] = __float2bfloat16(b.w);
  *(uint4*)d = *(const uint4*)t;
}
__global__ __launch_bounds__(256) void cvt_all(
    const float* __restrict__ x, const float* __restrict__ wq_a,
    const float* __restrict__ wq_b, const float* __restrict__ wkv_b,
    const float* __restrict__ wo, const float* __restrict__ wkv_a,
    bf16* __restrict__ xb, bf16* __restrict__ wqab, bf16* __restrict__ wqbb,
    bf16* __restrict__ wkvbb, bf16* __restrict__ wob, bf16* __restrict__ wkvab,
    bf16* __restrict__ wnT)
{
  const long ngrp = CVT_N6 / 8;
  for (long v = (long)blockIdx.x * 256 + threadIdx.x; v < ngrp; v += (long)gridDim.x * 256) {
    long i = v * 8;
    if (i < CVT_N0) {
      cvt8(x + i, xb + i);
    } else if (i < CVT_N1) {
      long j = i - CVT_N0; cvt8(wq_a + j, wqab + j);
    } else if (i < CVT_N2) {
      long j = i - CVT_N1; cvt8(wq_b + j, wqbb + j);
    } else if (i < CVT_N3) {
      long j = i - CVT_N2; cvt8(wkv_b + j, wkvbb + j);
    } else if (i < CVT_N4) {
      long j = i - CVT_N3; cvt8(wo + j, wob + j);
    } else if (i < CVT_N5) {
      long j = i - CVT_N4;
      if (j < (long)NKV_ * DIM_) cvt8(wkv_a + j, wkvab + j);
      else { __align__(16) bf16 t[8] = {}; *(uint4*)(wkvab + j) = *(const uint4*)t; }
    } else {
      long j = i - CVT_N5;                       // wnT[h][c][d] = wkv_b[(h*256+d)*512+c]
      int d = (int)(j & 127);
      long t2 = j >> 7;
      int c = (int)(t2 & 511);
      int h = (int)(t2 >> 9);
      __align__(16) bf16 t[8];
#pragma unroll
      for (int k = 0; k < 8; ++k)
        t[k] = __float2bfloat16(wkv_b[((long)(h * 256 + d + k)) * 512 + c]);
      *(uint4*)(wnT + j) = *(const uint4*)t;
    }
  }
}

// in-place RMSNorm of qa rows (1536), bf16
__global__ __launch_bounds__(256) void rmsnorm_qa(bf16* __restrict__ qa, const float* __restrict__ w) {
  long row = blockIdx.x;
  bf16* pr = qa + row * QL_;
  int tid = threadIdx.x, lane = tid & 63, wave = tid >> 6;
  float v[6]; float ss = 0.f;
#pragma unroll
  for (int k = 0; k < 6; ++k) { int c = tid + k * 256; v[k] = __bfloat162float(pr[c]); ss += v[k] * v[k]; }
  ss = wsum(ss);
  __shared__ float sred[4];
  if (lane == 0) sred[wave] = ss;
  __syncthreads();
  float tot = sred[0] + sred[1] + sred[2] + sred[3];
  float scl = rsqrtf(tot / (float)QL_ + 1e-6f);
#pragma unroll
  for (int k = 0; k < 6; ++k) { int c = tid + k * 256; pr[c] = __float2bfloat16(v[k] * scl * w[c]); }
}

// kv row postproc: RMSNorm(kv_c)*w -> k_full[0:512], rope(k_pe) -> k_full[512:576]
__global__ __launch_bounds__(256) void kv_post(const float* __restrict__ kvraw, const float* __restrict__ kvw,
                                               const float* __restrict__ cosb, const float* __restrict__ sinb,
                                               bf16* __restrict__ kfull) {
  int bs = blockIdx.x;
  int s = bs & (S_ - 1);
  const float* rowp = kvraw + (long)bs * NKVP_;
  bf16* outp = kfull + (long)bs * NKV_;
  int tid = threadIdx.x, lane = tid & 63, wave = tid >> 6;
  float v0 = rowp[tid], v1 = rowp[tid + 256];
  float ss = v0 * v0 + v1 * v1;
  ss = wsum(ss);
  __shared__ float sred[4];
  if (lane == 0) sred[wave] = ss;
  __syncthreads();
  float tot = sred[0] + sred[1] + sred[2] + sred[3];
  float scl = rsqrtf(tot / (float)KVL_ + 1e-6f);
  outp[tid]       = __float2bfloat16(v0 * scl * kvw[tid]);
  outp[tid + 256] = __float2bfloat16(v1 * scl * kvw[tid + 256]);
  if (tid < 32) {
    float x0 = rowp[KVL_ + 2 * tid], x1 = rowp[KVL_ + 2 * tid + 1];
    float c = cosb[s * 32 + tid], sn = sinb[s * 32 + tid];
    outp[KVL_ + 2 * tid]     = __float2bfloat16(x0 * c - x1 * sn);
    outp[KVL_ + 2 * tid + 1] = __float2bfloat16(x0 * sn + x1 * c);
  }
}

// rope(q_pe) for one (b, hc-head) chunk -> qfc[s*hc+hh][512:576]
__global__ __launch_bounds__(256) void q_post_chunk(const bf16* __restrict__ qsrc,
                                                    const float* __restrict__ cosb, const float* __restrict__ sinb,
                                                    bf16* __restrict__ qfc, int lg) {
  int tx = threadIdx.x & 31, ty = threadIdx.x >> 5;
  int idx = blockIdx.x * 8 + ty;        // 0..S*hc-1 = s*hc + hh
  int s = idx >> lg, hh = idx & ((1 << lg) - 1);
  const bf16* src = qsrc + (long)s * (H_ * DQK_) + hh * DQK_ + DN_;
  bf16* dst = qfc + (long)idx * NKV_ + KVL_;
  float x0 = __bfloat162float(src[2 * tx]), x1 = __bfloat162float(src[2 * tx + 1]);
  float c = cosb[s * 32 + tx], sn = sinb[s * 32 + tx];
  dst[2 * tx]     = __float2bfloat16(x0 * c - x1 * sn);
  dst[2 * tx + 1] = __float2bfloat16(x0 * sn + x1 * c);
}

// kv_cT[b][c][s] = k_full[b][s][c]  (c < 512)
__global__ __launch_bounds__(256) void transpose_kv(const bf16* __restrict__ kfull, bf16* __restrict__ kvT) {
  __shared__ bf16 tile[32][33];
  int b = blockIdx.z;
  int s0 = blockIdx.x * 32, c0 = blockIdx.y * 32;
  int tx = threadIdx.x & 31, ty = threadIdx.x >> 5;
#pragma unroll
  for (int r = 0; r < 4; ++r) {
    int s = s0 + ty + r * 8;
    tile[ty + r * 8][tx] = kfull[((long)b * S_ + s) * NKV_ + c0 + tx];
  }
  __syncthreads();
#pragma unroll
  for (int r = 0; r < 4; ++r) {
    int c = c0 + ty + r * 8;
    kvT[(long)b * KVL_ * S_ + (long)c * S_ + s0 + tx] = tile[tx][ty + r * 8];
  }
}

// causal softmax over one row of head-z, in place on bf16 scores (already
// scaled by SCALE_ in the scores-GEMM epilogue). Writes P rows zero-padded to
// the causal block edge (PV stages k < (r&~127)+128).
__global__ __launch_bounds__(256) void softmax_causal(bf16* __restrict__ sc) {
  int r = blockIdx.x, z = blockIdx.y;
  int tid = threadIdx.x, lane = tid & 63, wave = tid >> 6;
  bf16* row = sc + ((long)z * S_ + r) * S_;
  int wlen = (r & ~127) + 128;
  float v[8];
  float mx = -3.0e38f;
#pragma unroll
  for (int k = 0; k < 8; ++k) {
    int t = tid + k * 256;
    v[k] = (t <= r) ? __bfloat162float(row[t]) : -3.0e38f;
    mx = fmaxf(mx, v[k]);
  }
  __shared__ float smx[4];
#pragma unroll
  for (int o = 32; o > 0; o >>= 1) mx = fmaxf(mx, __shfl_down(mx, o, 64));
  if (lane == 0) smx[wave] = mx;
  __syncthreads();   // all reads of `row` complete before in-place writes
  mx = fmaxf(fmaxf(smx[0], smx[1]), fmaxf(smx[2], smx[3]));
  float s = 0.f;
#pragma unroll
  for (int k = 0; k < 8; ++k) {
    int t = tid + k * 256;
    v[k] = (t <= r) ? __expf(v[k] - mx) : 0.f;
    s += v[k];
  }
  s = wsum(s);
  __shared__ float ssm[4];
  if (lane == 0) ssm[wave] = s;
  __syncthreads();
  float inv = 1.f / (ssm[0] + ssm[1] + ssm[2] + ssm[3]);
#pragma unroll
  for (int k = 0; k < 8; ++k) {
    int t = tid + k * 256;
    if (t < wlen) row[t] = __float2bfloat16(v[k] * inv);
  }
}

// ---------------- attention loop (HC = heads per chunk, compile-time) -------
template <int HC>
static void attn_loop(hipStream_t stream, const bf16* qb, const bf16* wnT,
                      const bf16* kfull, const bf16* kvT, const bf16* wkvbb,
                      bf16* ovb, bf16* scores_c, bf16* qfull_c, bf16* ob_c,
                      const float* cosb, const float* sinb) {
  constexpr int LG = (HC == 16) ? 4 : (HC == 8) ? 3 : (HC == 4) ? 2 : 1;
  const int nch = B_ * (H_ / HC);
  for (int ch = 0; ch < nch; ++ch) {
    int b = ch / (H_ / HC), hq = ch % (H_ / HC), h0 = hq * HC;
    const bf16* qsrc = qb + (long)b * S_ * (H_ * DQK_) + (long)h0 * DQK_;

    // q_abs: qfull_c[s*HC+z][0:512] = q_nope(head h0+z) @ w_nopeT[h0+z]^T
    G<DN_, H_ * DQK_, DN_, HC * NKV_, 0>(stream,
        qsrc, DQK_, wnT + (long)h0 * KVL_ * DN_, (long)KVL_ * DN_,
        qfull_c, NKV_, S_, KVL_, HC);
    // rope(q_pe) -> qfull_c[s*HC+z][512:576]
    q_post_chunk<<<S_ * HC / 8, 256, 0, stream>>>(qsrc, cosb, sinb, qfull_c, LG);

    // scores = (qfull_c @ kfull^T) * SCALE_  (bf16 out, causal block skip)
    G<NKV_, HC * NKV_, NKV_, S_, 8 | 2>(stream,
        qfull_c, NKV_, kfull + (long)b * S_ * NKV_, 0,
        scores_c, (long)S_ * S_, S_, S_, HC);
    // softmax (in-place bf16)
    softmax_causal<<<dim3(S_, HC), 256, 0, stream>>>(scores_c);
    // PV: ob_c = P @ kv_cT^T  (causal K-limit)
    G<S_, S_, S_, HC * KVL_, 4>(stream,
        scores_c, (long)S_ * S_, kvT + (long)b * KVL_ * S_, 0,
        ob_c, KVL_, S_, KVL_, HC);
    // o @ w_v^T -> ovb rows/cols of this chunk
    G<KVL_, HC * KVL_, KVL_, H_ * DV_, 0>(stream,
        ob_c, KVL_, wkvbb + ((long)h0 * 256 + DN_) * KVL_, (long)256 * KVL_,
        ovb + (long)b * S_ * (H_ * DV_) + (long)h0 * DV_, DV_, S_, DV_, HC);
  }
}

// ---------------- host ----------------
extern "C" void kernel_launch(void* const* d_in, const int* in_sizes, int n_in,
                              void* d_out, int out_size, void* d_ws, size_t ws_size,
                              hipStream_t stream) {
  const float* x     = (const float*)d_in[0];
  const float* wq_a  = (const float*)d_in[1];
  const float* qnw   = (const float*)d_in[2];
  const float* wq_b  = (const float*)d_in[3];
  const float* wkv_a = (const float*)d_in[4];
  const float* kvnw  = (const float*)d_in[5];
  const float* wkv_b = (const float*)d_in[6];
  const float* wo    = (const float*)d_in[7];
  const float* cosb  = (const float*)d_in[8];
  const float* sinb  = (const float*)d_in[9];
  float* out = (float*)d_out;
  (void)in_sizes; (void)n_in; (void)out_size;

  // heads per attention chunk, from ws_size (constant per session -> graph-safe).
  // loop overlay/head = scores 8,388,608 + qfull 2,359,296 + ob 2,097,152
  //                   = 12,845,056 B; required = 65,536,000 + max(45,088,768, hc*12,845,056)
  int hc;
  if      (ws_size >= 271056896UL) hc = 16;
  else if (ws_size >= 168296448UL) hc = 8;
  else if (ws_size >= 116916224UL) hc = 4;
  else                             hc = 2;

  // ---- workspace: persistent region first, E/loop overlay after ----
  char* base = (char*)d_ws;
  long off = 0;
  auto at = [&](long bytes) { char* r = base + off; off += bytes; return r; };

  // P region (persistent across the whole call) -- 65,536,000 B
  bf16* qb    = (bf16*)at(25165824L);   // 4096x3072 bf16
  bf16* ovb   = (bf16*)at(16777216L);   // 4096x2048 bf16
  bf16* kfull = (bf16*)at(4718592L);    // 4096x576  bf16
  bf16* kvT   = (bf16*)at(4194304L);    // 2x512x2048 bf16
  bf16* wkvbb = (bf16*)at(4194304L);    // 4096x512  bf16
  bf16* wnT   = (bf16*)at(2097152L);    // 16x512x128 bf16
  bf16* wob   = (bf16*)at(8388608L);    // 2048x2048 bf16
  char* ov = base + off;                // overlay region

  // E overlay (early phase; all dead before the attention loop)
  bf16*  xb    = (bf16*) (ov);                 // 4096x2048 bf16  (16.8MB)
  bf16*  wqab  = (bf16*) (ov + 16777216L);     // 1536x2048 bf16  (6.3MB)
  bf16*  wqbb  = (bf16*) (ov + 23068672L);     // 3072x1536 bf16  (9.4MB)
  bf16*  qa    = (bf16*) (ov + 32505856L);     // 4096x1536 bf16  (12.6MB)
  float* kvraw = (float*)qa;                   // overlay on qa (10.5MB), qa dead first

  // loop overlay (attention phase)
  bf16* scores_c = (bf16*)ov;                                     // hc x 2048x2048 bf16
  bf16* qfull_c  = (bf16*)(ov + (long)hc * 8388608L);             // 2048 x hc x 576 bf16
  bf16* ob_c     = (bf16*)(ov + (long)hc * (8388608L + 2359296L));// 2048 x hc x 512 bf16

  // wkv_a (bf16, padded 576->640 rows) temporarily lives in kvT, which is
  // only written by transpose_kv AFTER the kv GEMM consumed it.
  bf16* wkvab = kvT;   // 640*2048*2 = 2.62MB <= 4.19MB

  // one fused, vectorized conversion pass
  cvt_all<<<4096, 256, 0, stream>>>(x, wq_a, wq_b, wkv_b, wo, wkv_a,
                                    xb, wqab, wqbb, wkvbb, wob, wkvab, wnT);

  // q path: qa = x@wq_a^T -> rmsnorm -> qb = qa@wq_b^T
  G<DIM_, DIM_, DIM_, QL_, 0>(stream, xb, 0, wqab, 0, qa, 0, BS_, QL_, 1);
  rmsnorm_qa<<<BS_, 256, 0, stream>>>(qa, qnw);
  G<QL_, QL_, QL_, H_ * DQK_, 0>(stream, qa, 0, wqbb, 0, qb, 0, BS_, H_ * DQK_, 1);

  // kv path: kvraw = x@wkv_a^T (padded, fp32) -> norm+rope -> kfull, kvT
  G<DIM_, DIM_, DIM_, NKVP_, 1>(stream, xb, 0, wkvab, 0, kvraw, 0, BS_, NKVP_, 1);
  kv_post<<<BS_, 256, 0, stream>>>(kvraw, kvnw, cosb, sinb, kfull);
  transpose_kv<<<dim3(S_ / 32, KVL_ / 32, B_), 256, 0, stream>>>(kfull, kvT);

  // attention chunks
  if (hc == 16)
    attn_loop<16>(stream, qb, wnT, kfull, kvT, wkvbb, ovb, scores_c, qfull_c, ob_c, cosb, sinb);
  else if (hc == 8)
    attn_loop<8>(stream, qb, wnT, kfull, kvT, wkvbb, ovb, scores_c, qfull_c, ob_c, cosb, sinb);
  else if (hc == 4)
    attn_loop<4>(stream, qb, wnT, kfull, kvT, wkvbb, ovb, scores_c, qfull_c, ob_c, cosb, sinb);
  else
    attn_loop<2>(stream, qb, wnT, kfull, kvT, wkvbb, ovb, scores_c, qfull_c, ob_c, cosb, sinb);

  // final projection: out = ovb @ wo^T (fp32 out)
  G<H_ * DV_, H_ * DV_, H_ * DV_, DIM_, 1>(stream, ovb, 0, wob, 0, out, 0, BS_, DIM_, 1);
}

// Round 7
// 714.984 us; speedup vs baseline: 2.4357x; 1.2092x over previous
//
#include <hip/hip_runtime.h>
#include <hip/hip_bf16.h>
#include <stdint.h>

// ---------------- problem constants ----------------
#define B_    2
#define S_    2048
#define DIM_  2048
#define H_    16
#define QL_   1536
#define KVL_  512
#define DN_   128
#define DR_   64
#define DV_   128
#define DQK_  192
#define NKV_  576     // KVL_ + DR_
#define NKVP_ 640     // padded to multiple of 128
#define BS_   (B_*S_)
#define SCALE_ 0.07216878364870322f   // 192^-0.5

typedef __hip_bfloat16 bf16;
typedef float f32x4 __attribute__((ext_vector_type(4)));
typedef short bf16x8 __attribute__((ext_vector_type(8)));   // 8 bf16 (4 VGPRs)

// ---------------- GEMM (C = A @ B^T), m97-style, shape-specialized ----------
#define BMT 128
#define BNT 128
#define BKT 64

__device__ __forceinline__ void gload_lds16(const void* g, void* l) {
#if __has_builtin(__builtin_amdgcn_global_load_lds)
  __builtin_amdgcn_global_load_lds(
      (const __attribute__((address_space(1))) void*)g,
      (__attribute__((address_space(3))) void*)l, 16, 0, 0);
#else
  *(uint4*)l = *(const uint4*)g;
#endif
}

// A: M x K (row-major, LDA), B: N x K (row-major, LDB) -> C: M x N (LDC)
// FLAGS: 1 = fp32 C, 8 = bf16 C scaled by SCALE_, else bf16 C;
//        2 = causal block skip (scores), 4 = causal K-limit (PV).
template <int K, int LDA, int LDB, int LDC, int FLAGS>
__global__ __launch_bounds__(256) void gemm_t(
    const bf16* __restrict__ A, long saz,
    const bf16* __restrict__ Bm, long sbz,
    void* __restrict__ Cv, long scz)
{
  int z = blockIdx.z;
  A  += (long)z * saz;
  Bm += (long)z * sbz;
  long coff = (long)z * scz;

  int row0 = blockIdx.y * BMT, col0 = blockIdx.x * BNT;
  if (FLAGS & 2) { if (col0 > row0 + (BMT - 1)) return; }   // fully masked block
  int kend = K;
  if (FLAGS & 4) { int lim = row0 + BMT; if (lim < kend) kend = lim; }

  // LDS: [128 rows][8 x 16B chunks], chunk j stored at jx = j ^ (row&7):
  // staging stays lane-contiguous (wave-uniform base + lane*16) and
  // ds_read_b128 sees <=2-way bank conflicts (free, m136).
  __shared__ __align__(16) bf16 Asm[BMT * BKT];
  __shared__ __align__(16) bf16 Bsm[BNT * BKT];

  int tid = threadIdx.x, lane = tid & 63, wave = tid >> 6;
  int wm = (wave >> 1) * 64, wn = (wave & 1) * 64;
  int quad = lane >> 4, l16 = lane & 15;

  f32x4 acc[4][4] = {};

  for (int k0 = 0; k0 < kend; k0 += BKT) {
    __syncthreads();
#pragma unroll
    for (int t = 0; t < 4; ++t) {
      int c = (wave * 4 + t) * 64 + lane;        // 16B chunk id 0..1023
      int m = c >> 3, jx = c & 7, j = jx ^ (m & 7);
      gload_lds16(A  + (long)((row0 + m) * LDA + k0 + j * 8), Asm + c * 8);
      gload_lds16(Bm + (long)((col0 + m) * LDB + k0 + j * 8), Bsm + c * 8);
    }
    __syncthreads();
#pragma unroll
    for (int kk = 0; kk < BKT; kk += 32) {
      int jl = (kk >> 3) + quad;
      bf16x8 af[4], bfv[4];
#pragma unroll
      for (int i = 0; i < 4; ++i) {
        int m = wm + i * 16 + l16;
        af[i]  = *(const bf16x8*)(Asm + m * 64 + ((jl ^ (m & 7)) * 8));
        int n = wn + i * 16 + l16;
        bfv[i] = *(const bf16x8*)(Bsm + n * 64 + ((jl ^ (n & 7)) * 8));
      }
#pragma unroll
      for (int i = 0; i < 4; ++i)
#pragma unroll
        for (int jn = 0; jn < 4; ++jn)
          acc[i][jn] = __builtin_amdgcn_mfma_f32_16x16x32_bf16(af[i], bfv[jn], acc[i][jn], 0, 0, 0);
    }
  }

  // epilogue: C/D layout col=lane&15, row=quad*4+reg (m89/m91 verified)
  if (FLAGS & 1) {
    float* C = (float*)Cv + coff;
#pragma unroll
    for (int i = 0; i < 4; ++i)
#pragma unroll
      for (int jn = 0; jn < 4; ++jn)
#pragma unroll
        for (int r = 0; r < 4; ++r) {
          int rr = row0 + wm + i * 16 + quad * 4 + r;
          int cc = col0 + wn + jn * 16 + l16;
          C[(long)rr * LDC + cc] = acc[i][jn][r];
        }
  } else if (FLAGS & 8) {
    bf16* C = (bf16*)Cv + coff;
#pragma unroll
    for (int i = 0; i < 4; ++i)
#pragma unroll
      for (int jn = 0; jn < 4; ++jn)
#pragma unroll
        for (int r = 0; r < 4; ++r) {
          int rr = row0 + wm + i * 16 + quad * 4 + r;
          int cc = col0 + wn + jn * 16 + l16;
          C[(long)rr * LDC + cc] = __float2bfloat16(acc[i][jn][r] * SCALE_);
        }
  } else {
    bf16* C = (bf16*)Cv + coff;
#pragma unroll
    for (int i = 0; i < 4; ++i)
#pragma unroll
      for (int jn = 0; jn < 4; ++jn)
#pragma unroll
        for (int r = 0; r < 4; ++r) {
          int rr = row0 + wm + i * 16 + quad * 4 + r;
          int cc = col0 + wn + jn * 16 + l16;
          C[(long)rr * LDC + cc] = __float2bfloat16(acc[i][jn][r]);
        }
  }
}

template <int K, int LDA, int LDB, int LDC, int FLAGS>
static inline void G(hipStream_t st, const bf16* A, long saz, const bf16* Bp, long sbz,
                     void* C, long scz, int M, int N, int Z) {
  dim3 g(N / BNT, M / BMT, Z);
  gemm_t<K, LDA, LDB, LDC, FLAGS><<<g, 256, 0, st>>>(A, saz, Bp, sbz, C, scz);
}

// ---------------- helpers ----------------
__device__ __forceinline__ float wsum(float v) {
#pragma unroll
  for (int o = 32; o > 0; o >>= 1) v += __shfl_down(v, o, 64);
  return v;
}

// fused fp32->bf16 conversion pass, vectorized: 8 elements (two float4 loads,
// one 16B bf16x8 store) per group. All segment bases/sizes are multiples of 8
// elements; pad boundary (1,179,648) is also 8-aligned.
#define CVT_N0  8388608L    // x -> xb            (4096*2048)
#define CVT_N1 11534336L    // wq_a -> wqab       (+1536*2048)
#define CVT_N2 16252928L    // wq_b -> wqbb       (+3072*1536)
#define CVT_N3 18350080L    // wkv_b -> wkvbb     (+4096*512)
#define CVT_N4 22544384L    // wo -> wob          (+2048*2048)
#define CVT_N5 23855104L    // wkv_a pad -> wkvab (+640*2048, valid 1179648)
__device__ __forceinline__ void cvt8(const float* __restrict__ s, bf16* __restrict__ d) {
  float4 a = ((const float4*)s)[0], b = ((const float4*)s)[1];
  __align__(16) bf16 t[8];
  t[0] = __float2bfloat16(a.x); t[1] = __float2bfloat16(a.y);
  t[2] = __float2bfloat16(a.z); t[3] = __float2bfloat16(a.w);
  t[4] = __float2bfloat16(b.x); t[5] = __float2bfloat16(b.y);
  t[6] = __float2bfloat16(b.z); t[7] = __float2bfloat16(b.w);
  *(uint4*)d = *(const uint4*)t;
}
__global__ __launch_bounds__(256) void cvt_all(
    const float* __restrict__ x, const float* __restrict__ wq_a,
    const float* __restrict__ wq_b, const float* __restrict__ wkv_b,
    const float* __restrict__ wo, const float* __restrict__ wkv_a,
    bf16* __restrict__ xb, bf16* __restrict__ wqab, bf16* __restrict__ wqbb,
    bf16* __restrict__ wkvbb, bf16* __restrict__ wob, bf16* __restrict__ wkvab)
{
  const long ngrp = CVT_N5 / 8;
  for (long v = (long)blockIdx.x * 256 + threadIdx.x; v < ngrp; v += (long)gridDim.x * 256) {
    long i = v * 8;
    if (i < CVT_N0) {
      cvt8(x + i, xb + i);
    } else if (i < CVT_N1) {
      long j = i - CVT_N0; cvt8(wq_a + j, wqab + j);
    } else if (i < CVT_N2) {
      long j = i - CVT_N1; cvt8(wq_b + j, wqbb + j);
    } else if (i < CVT_N3) {
      long j = i - CVT_N2; cvt8(wkv_b + j, wkvbb + j);
    } else if (i < CVT_N4) {
      long j = i - CVT_N3; cvt8(wo + j, wob + j);
    } else {
      long j = i - CVT_N4;
      if (j < (long)NKV_ * DIM_) cvt8(wkv_a + j, wkvab + j);
      else { __align__(16) bf16 t[8] = {}; *(uint4*)(wkvab + j) = *(const uint4*)t; }
    }
  }
}

// in-place RMSNorm of qa rows (1536), bf16
__global__ __launch_bounds__(256) void rmsnorm_qa(bf16* __restrict__ qa, const float* __restrict__ w) {
  long row = blockIdx.x;
  bf16* pr = qa + row * QL_;
  int tid = threadIdx.x, lane = tid & 63, wave = tid >> 6;
  float v[6]; float ss = 0.f;
#pragma unroll
  for (int k = 0; k < 6; ++k) { int c = tid + k * 256; v[k] = __bfloat162float(pr[c]); ss += v[k] * v[k]; }
  ss = wsum(ss);
  __shared__ float sred[4];
  if (lane == 0) sred[wave] = ss;
  __syncthreads();
  float tot = sred[0] + sred[1] + sred[2] + sred[3];
  float scl = rsqrtf(tot / (float)QL_ + 1e-6f);
#pragma unroll
  for (int k = 0; k < 6; ++k) { int c = tid + k * 256; pr[c] = __float2bfloat16(v[k] * scl * w[c]); }
}

// kv row postproc: RMSNorm(kv_c)*w -> k_full[0:512], rope(k_pe) -> k_full[512:576]
__global__ __launch_bounds__(256) void kv_post(const float* __restrict__ kvraw, const float* __restrict__ kvw,
                                               const float* __restrict__ cosb, const float* __restrict__ sinb,
                                               bf16* __restrict__ kfull) {
  int bs = blockIdx.x;
  int s = bs & (S_ - 1);
  const float* rowp = kvraw + (long)bs * NKVP_;
  bf16* outp = kfull + (long)bs * NKV_;
  int tid = threadIdx.x, lane = tid & 63, wave = tid >> 6;
  float v0 = rowp[tid], v1 = rowp[tid + 256];
  float ss = v0 * v0 + v1 * v1;
  ss = wsum(ss);
  __shared__ float sred[4];
  if (lane == 0) sred[wave] = ss;
  __syncthreads();
  float tot = sred[0] + sred[1] + sred[2] + sred[3];
  float scl = rsqrtf(tot / (float)KVL_ + 1e-6f);
  outp[tid]       = __float2bfloat16(v0 * scl * kvw[tid]);
  outp[tid + 256] = __float2bfloat16(v1 * scl * kvw[tid + 256]);
  if (tid < 32) {
    float x0 = rowp[KVL_ + 2 * tid], x1 = rowp[KVL_ + 2 * tid + 1];
    float c = cosb[s * 32 + tid], sn = sinb[s * 32 + tid];
    outp[KVL_ + 2 * tid]     = __float2bfloat16(x0 * c - x1 * sn);
    outp[KVL_ + 2 * tid + 1] = __float2bfloat16(x0 * sn + x1 * c);
  }
}

// rope(q_pe) applied in place on qb[bs][h*192+128 .. +191], all heads/rows.
__global__ __launch_bounds__(256) void rope_q(bf16* __restrict__ qb,
                                              const float* __restrict__ cosb,
                                              const float* __restrict__ sinb) {
  int tx = threadIdx.x & 31, ty = threadIdx.x >> 5;
  long row = (long)blockIdx.x * 8 + ty;     // 0..BS_*H_-1
  long bs = row >> 4; int h = (int)(row & 15); int s = (int)(bs & (S_ - 1));
  bf16* p = qb + bs * (H_ * DQK_) + h * DQK_ + DN_;
  float x0 = __bfloat162float(p[2 * tx]), x1 = __bfloat162float(p[2 * tx + 1]);
  float c = cosb[s * 32 + tx], sn = sinb[s * 32 + tx];
  p[2 * tx]     = __float2bfloat16(x0 * c - x1 * sn);
  p[2 * tx + 1] = __float2bfloat16(x0 * sn + x1 * c);
}

// kvabs[b,h,t,128:192] = kfull[b,t,512:576] (k_pe, already roped)
__global__ __launch_bounds__(256) void kpe_fill(const bf16* __restrict__ kfull, bf16* __restrict__ kvabs) {
  const long n = (long)B_ * H_ * S_ * 64;
  for (long i = (long)blockIdx.x * 256 + threadIdx.x; i < n; i += (long)gridDim.x * 256) {
    int d = (int)(i & 63);
    long t = (i >> 6) & (S_ - 1);
    int h = (int)((i >> 17) & 15);
    int b = (int)(i >> 21);
    kvabs[(((long)(b * H_ + h) * S_) + t) * DQK_ + DN_ + d] =
        kfull[((long)b * S_ + t) * NKV_ + KVL_ + d];
  }
}

// kv_cT[b][c][s] = k_full[b][s][c]  (c < 512)
__global__ __launch_bounds__(256) void transpose_kv(const bf16* __restrict__ kfull, bf16* __restrict__ kvT) {
  __shared__ bf16 tile[32][33];
  int b = blockIdx.z;
  int s0 = blockIdx.x * 32, c0 = blockIdx.y * 32;
  int tx = threadIdx.x & 31, ty = threadIdx.x >> 5;
#pragma unroll
  for (int r = 0; r < 4; ++r) {
    int s = s0 + ty + r * 8;
    tile[ty + r * 8][tx] = kfull[((long)b * S_ + s) * NKV_ + c0 + tx];
  }
  __syncthreads();
#pragma unroll
  for (int r = 0; r < 4; ++r) {
    int c = c0 + ty + r * 8;
    kvT[(long)b * KVL_ * S_ + (long)c * S_ + s0 + tx] = tile[tx][ty + r * 8];
  }
}

// causal softmax over one row of head-z, in place on bf16 scores (already
// scaled by SCALE_ in the scores-GEMM epilogue). Block-uniform chunk skip:
// chunk k touched only if k*256 <= r. Writes zero-padded to the causal block
// edge wlen=(r&~127)+128 (PV stages k < row0+128 <= wlen).
__global__ __launch_bounds__(256) void softmax_causal(bf16* __restrict__ sc) {
  int r = blockIdx.x, z = blockIdx.y;
  int tid = threadIdx.x, lane = tid & 63, wave = tid >> 6;
  bf16* row = sc + ((long)z * S_ + r) * S_;
  int wlen = (r & ~127) + 128;
  float v[8] = {};
  float mx = -3.0e38f;
#pragma unroll
  for (int k = 0; k < 8; ++k) {
    if (k * 256 <= r) {               // block-uniform
      int t = tid + k * 256;
      v[k] = (t <= r) ? __bfloat162float(row[t]) : -3.0e38f;
      mx = fmaxf(mx, v[k]);
    }
  }
  __shared__ float smx[4];
#pragma unroll
  for (int o = 32; o > 0; o >>= 1) mx = fmaxf(mx, __shfl_down(mx, o, 64));
  if (lane == 0) smx[wave] = mx;
  __syncthreads();   // all reads of `row` complete before in-place writes
  mx = fmaxf(fmaxf(smx[0], smx[1]), fmaxf(smx[2], smx[3]));
  float s = 0.f;
#pragma unroll
  for (int k = 0; k < 8; ++k) {
    if (k * 256 <= r) {
      int t = tid + k * 256;
      v[k] = (t <= r) ? __expf(v[k] - mx) : 0.f;
      s += v[k];
    }
  }
  s = wsum(s);
  __shared__ float ssm[4];
  if (lane == 0) ssm[wave] = s;
  __syncthreads();
  float inv = 1.f / (ssm[0] + ssm[1] + ssm[2] + ssm[3]);
#pragma unroll
  for (int k = 0; k < 8; ++k) {
    int t = tid + k * 256;
    if (t < wlen) row[t] = __float2bfloat16(v[k] * inv);
  }
}

// ---------------- attention loop (HC = heads per chunk, compile-time) -------
// scores = [q_nope | roped q_pe] @ [kv_abs | k_pe]^T  (K = 192, k-side absorbed)
template <int HC>
static void attn_loop(hipStream_t stream, const bf16* qb, const bf16* kvabs,
                      const bf16* kvT, const bf16* wkvbb,
                      bf16* ovb, bf16* scores_c, bf16* ob_c) {
  const int nch = B_ * (H_ / HC);
  for (int ch = 0; ch < nch; ++ch) {
    int b = ch / (H_ / HC), hq = ch % (H_ / HC), h0 = hq * HC;

    // scores (bf16 out scaled by SCALE_, causal block skip), all HC heads in z
    G<DQK_, H_ * DQK_, DQK_, S_, 8 | 2>(stream,
        qb + (long)b * S_ * (H_ * DQK_) + (long)h0 * DQK_, DQK_,
        kvabs + (long)(b * H_ + h0) * S_ * DQK_, (long)S_ * DQK_,
        scores_c, (long)S_ * S_, S_, S_, HC);
    // softmax (in-place bf16)
    softmax_causal<<<dim3(S_, HC), 256, 0, stream>>>(scores_c);
    // PV: ob_c = P @ kv_cT^T  (causal K-limit)
    G<S_, S_, S_, HC * KVL_, 4>(stream,
        scores_c, (long)S_ * S_, kvT + (long)b * KVL_ * S_, 0,
        ob_c, KVL_, S_, KVL_, HC);
    // o @ w_v^T -> ovb rows/cols of this chunk
    G<KVL_, HC * KVL_, KVL_, H_ * DV_, 0>(stream,
        ob_c, KVL_, wkvbb + ((long)h0 * 256 + DN_) * KVL_, (long)256 * KVL_,
        ovb + (long)b * S_ * (H_ * DV_) + (long)h0 * DV_, DV_, S_, DV_, HC);
  }
}

// ---------------- host ----------------
extern "C" void kernel_launch(void* const* d_in, const int* in_sizes, int n_in,
                              void* d_out, int out_size, void* d_ws, size_t ws_size,
                              hipStream_t stream) {
  const float* x     = (const float*)d_in[0];
  const float* wq_a  = (const float*)d_in[1];
  const float* qnw   = (const float*)d_in[2];
  const float* wq_b  = (const float*)d_in[3];
  const float* wkv_a = (const float*)d_in[4];
  const float* kvnw  = (const float*)d_in[5];
  const float* wkv_b = (const float*)d_in[6];
  const float* wo    = (const float*)d_in[7];
  const float* cosb  = (const float*)d_in[8];
  const float* sinb  = (const float*)d_in[9];
  float* out = (float*)d_out;
  (void)in_sizes; (void)n_in; (void)out_size;

  // heads per attention chunk, from ws_size (constant per session -> graph-safe).
  // P = 88,604,672; E overlay = 45,088,768; loop overlay/head = 10,485,760.
  // hc=16: 256,376,832; hc=8: 172,490,752; hc=4: 133,693,440 (E dominates).
  int hc;
  if      (ws_size >= 256376832UL) hc = 16;
  else if (ws_size >= 172490752UL) hc = 8;
  else                             hc = 4;

  // ---- workspace: persistent region first, E/loop overlay after ----
  char* base = (char*)d_ws;
  long off = 0;
  auto at = [&](long bytes) { char* r = base + off; off += bytes; return r; };

  // P region (persistent across the whole call) -- 88,604,672 B
  bf16* qb    = (bf16*)at(25165824L);   // 4096x3072 bf16 (rope applied in place)
  bf16* ovb   = (bf16*)at(16777216L);   // 4096x2048 bf16
  bf16* kfull = (bf16*)at(4718592L);    // 4096x576  bf16
  bf16* kvT   = (bf16*)at(4194304L);    // 2x512x2048 bf16
  bf16* wkvbb = (bf16*)at(4194304L);    // 4096x512  bf16
  bf16* wob   = (bf16*)at(8388608L);    // 2048x2048 bf16
  bf16* kvabs = (bf16*)at(25165824L);   // 2x16x2048x192 bf16 [kv_abs | k_pe]
  char* ov = base + off;                // overlay region

  // E overlay (early phase; all dead before the attention loop)
  bf16*  xb    = (bf16*) (ov);                 // 4096x2048 bf16  (16.8MB)
  bf16*  wqab  = (bf16*) (ov + 16777216L);     // 1536x2048 bf16  (6.3MB)
  bf16*  wqbb  = (bf16*) (ov + 23068672L);     // 3072x1536 bf16  (9.4MB)
  bf16*  qa    = (bf16*) (ov + 32505856L);     // 4096x1536 bf16  (12.6MB)
  float* kvraw = (float*)qa;                   // overlay on qa (10.5MB), qa dead first

  // loop overlay (attention phase)
  bf16* scores_c = (bf16*)ov;                          // hc x 2048x2048 bf16
  bf16* ob_c     = (bf16*)(ov + (long)hc * 8388608L);  // 2048 x hc x 512 bf16

  // wkv_a (bf16, padded 576->640 rows) temporarily lives in kvT, which is
  // only written by transpose_kv AFTER the kv GEMM consumed it.
  bf16* wkvab = kvT;   // 640*2048*2 = 2.62MB <= 4.19MB

  // one fused, vectorized conversion pass
  cvt_all<<<4096, 256, 0, stream>>>(x, wq_a, wq_b, wkv_b, wo, wkv_a,
                                    xb, wqab, wqbb, wkvbb, wob, wkvab);

  // q path: qa = x@wq_a^T -> rmsnorm -> qb = qa@wq_b^T -> rope q_pe in place
  G<DIM_, DIM_, DIM_, QL_, 0>(stream, xb, 0, wqab, 0, qa, 0, BS_, QL_, 1);
  rmsnorm_qa<<<BS_, 256, 0, stream>>>(qa, qnw);
  G<QL_, QL_, QL_, H_ * DQK_, 0>(stream, qa, 0, wqbb, 0, qb, 0, BS_, H_ * DQK_, 1);
  rope_q<<<BS_ * H_ / 8, 256, 0, stream>>>(qb, cosb, sinb);

  // kv path: kvraw = x@wkv_a^T (padded, fp32) -> norm+rope -> kfull, kvT
  G<DIM_, DIM_, DIM_, NKVP_, 1>(stream, xb, 0, wkvab, 0, kvraw, 0, BS_, NKVP_, 1);
  kv_post<<<BS_, 256, 0, stream>>>(kvraw, kvnw, cosb, sinb, kfull);
  transpose_kv<<<dim3(S_ / 32, KVL_ / 32, B_), 256, 0, stream>>>(kfull, kvT);

  // k-side absorption: kvabs[b,h,t,0:128] = kv_c[b,t,:] @ w_nope[h]^T
  // (A = kfull rows, lda=576, K=512; B = w_nope[h] = wkvbb rows h*256..h*256+127)
  for (int b = 0; b < B_; ++b)
    G<KVL_, NKV_, KVL_, DQK_, 0>(stream,
        kfull + (long)b * S_ * NKV_, 0, wkvbb, (long)256 * KVL_,
        kvabs + (long)b * H_ * S_ * DQK_, (long)S_ * DQK_, S_, DN_, H_);
  // kvabs[b,h,t,128:192] = k_pe (roped, shared across heads)
  kpe_fill<<<8192, 256, 0, stream>>>(kfull, kvabs);

  // attention chunks
  if (hc == 16)
    attn_loop<16>(stream, qb, kvabs, kvT, wkvbb, ovb, scores_c, ob_c);
  else if (hc == 8)
    attn_loop<8>(stream, qb, kvabs, kvT, wkvbb, ovb, scores_c, ob_c);
  else
    attn_loop<4>(stream, qb, kvabs, kvT, wkvbb, ovb, scores_c, ob_c);

  // final projection: out = ovb @ wo^T (fp32 out)
  G<H_ * DV_, H_ * DV_, H_ * DV_, DIM_, 1>(stream, ovb, 0, wob, 0, out, 0, BS_, DIM_, 1);
}